// Round 2
// baseline (992.483 us; speedup 1.0000x reference)
//
#include <hip/hip_runtime.h>
#include <hip/hip_bf16.h>

#define NNODES 50000
#define NREL   16
#define NEDGE  400000
#define BN_EPS 1e-5f
#define M_REAL NNODES
#define M_TILES 391            /* ceil(50000/128) */
#define RPX    49              /* ceil(391/8) row-blocks per XCD */
#define GRIDB  (8 * RPX * 2)   /* 784 blocks; 4 blocks/CU capacity = 1024 */
#define SCAN_B 512
#define SCAN_NB ((NNODES + SCAN_B - 1) / SCAN_B)   /* 98 */

typedef __attribute__((ext_vector_type(8))) short short8;
typedef __attribute__((ext_vector_type(4))) float f4;

__device__ __forceinline__ float bf2f(unsigned short u) {
    union { unsigned int i; float f; } x; x.i = ((unsigned int)u) << 16; return x.f;
}
__device__ __forceinline__ unsigned short f2bf(float f) {
    __hip_bfloat16 h = __float2bfloat16(f);
    union { __hip_bfloat16 h; unsigned short u; } x; x.h = h; return x.u;
}

__device__ __forceinline__ void g2l16(const unsigned short* g, unsigned short* l) {
    __builtin_amdgcn_global_load_lds(
        (const __attribute__((address_space(1))) unsigned int*)g,
        (__attribute__((address_space(3))) unsigned int*)l,
        16, 0, 0);
}

// ---------------------------------------------------------------------------
// FUSED GEMM + BN + relu, normal launch with MANUAL grid barrier.
// All 784 blocks are co-resident (32KB LDS, <=128 VGPR -> 4 blocks/CU -> 1024
// slots), so an atomic arrive+spin barrier is deadlock-free.
// Tile y = A[M,K] @ WT[256,K]^T + bias stays in registers; BN column stats via
// device atomics; barrier; BN+relu in-register; bf16 straight into next
// layer's gather buffer (stride 768, offset 512) or f32 to d_out (last).
// NOTE: inactive blocks (row_blk>=M_TILES) must still reach the barrier.
// ---------------------------------------------------------------------------
template<int K, bool LAST>
__global__ __launch_bounds__(256, 4) void gemmf_k(
    const unsigned short* __restrict__ A,
    const unsigned short* __restrict__ WT,
    const float* __restrict__ bias,
    float* __restrict__ bns,
    const float* __restrict__ gamma,
    const float* __restrict__ beta,
    unsigned short* __restrict__ xn,
    float* __restrict__ outp,
    unsigned int* __restrict__ bar)
{
    const int lin = blockIdx.x;
    const int xcd = lin & 7;
    const int idx = lin >> 3;
    const int row_blk = xcd * RPX + (idx >> 1);
    const int nt = idx & 1;
    const bool active = (row_blk < M_TILES);
    const int tile_m = row_blk * 128;
    const int tile_n = nt * 128;

    __shared__ unsigned short As[128 * 64];
    __shared__ unsigned short Bs[128 * 64];

    const int w = threadIdx.x >> 6;
    const int l = threadIdx.x & 63;
    const int lm = l & 15;
    const int kq = l >> 4;
    const int wm = (w & 1) << 6;
    const int wn = (w >> 1) << 6;

    f4 acc[4][4];
#pragma unroll
    for (int mi = 0; mi < 4; ++mi)
#pragma unroll
        for (int ni = 0; ni < 4; ++ni) acc[mi][ni] = (f4){0.f, 0.f, 0.f, 0.f};

    int cols[4];

    if (active) {
        const int lrow = l >> 3;
        const int chunk = ((l & 7) + 8 - lrow) & 7;
        const unsigned short* srcA[4];
        const unsigned short* srcB[4];
        unsigned short* dstA[4];
        unsigned short* dstB[4];
#pragma unroll
        for (int it = 0; it < 4; ++it) {
            int rt = it * 32 + w * 8 + lrow;
            int rg = tile_m + rt; if (rg >= M_REAL) rg = M_REAL - 1;
            srcA[it] = A  + (size_t)rg * K + chunk * 8;
            srcB[it] = WT + (size_t)(tile_n + rt) * K + chunk * 8;
            dstA[it] = As + (it * 32 + w * 8) * 64;
            dstB[it] = Bs + (it * 32 + w * 8) * 64;
        }

        unsigned aoff[4], boff[4];
#pragma unroll
        for (int mi = 0; mi < 4; ++mi) {
            aoff[mi] = (unsigned)((wm + mi * 16 + lm) * 128 + (((kq + lm) & 7) << 4));
            boff[mi] = (unsigned)((wn + mi * 16 + lm) * 128 + (((kq + lm) & 7) << 4));
        }

        for (int kc = 0; kc < K; kc += 64) {
#pragma unroll
            for (int it = 0; it < 4; ++it) {
                g2l16(srcA[it] + kc, dstA[it]);
                g2l16(srcB[it] + kc, dstB[it]);
            }
            __syncthreads();
#pragma unroll
            for (int kh = 0; kh < 2; ++kh) {
                const unsigned x = kh << 6;
                short8 af[4], bfr[4];
#pragma unroll
                for (int mi = 0; mi < 4; ++mi)
                    af[mi] = *(const short8*)((const char*)As + (aoff[mi] ^ x));
#pragma unroll
                for (int ni = 0; ni < 4; ++ni)
                    bfr[ni] = *(const short8*)((const char*)Bs + (boff[ni] ^ x));
#pragma unroll
                for (int mi = 0; mi < 4; ++mi)
#pragma unroll
                    for (int ni = 0; ni < 4; ++ni)
                        acc[mi][ni] = __builtin_amdgcn_mfma_f32_16x16x32_bf16(
                            af[mi], bfr[ni], acc[mi][ni], 0, 0, 0);
            }
            __syncthreads();
        }

        // bias add in-register + column stats
        float bv[4];
#pragma unroll
        for (int ni = 0; ni < 4; ++ni) {
            cols[ni] = tile_n + wn + ni * 16 + lm;
            bv[ni] = bias[cols[ni]];
        }
        float s1[4] = {0.f, 0.f, 0.f, 0.f}, s2[4] = {0.f, 0.f, 0.f, 0.f};
#pragma unroll
        for (int mi = 0; mi < 4; ++mi) {
#pragma unroll
            for (int rg = 0; rg < 4; ++rg) {
                int row = tile_m + wm + mi * 16 + kq * 4 + rg;
                if (row < M_REAL) {
#pragma unroll
                    for (int ni = 0; ni < 4; ++ni) {
                        float v = acc[mi][ni][rg] + bv[ni];
                        acc[mi][ni][rg] = v;
                        s1[ni] += v; s2[ni] += v * v;
                    }
                }
            }
        }
#pragma unroll
        for (int ni = 0; ni < 4; ++ni) {
            float a = s1[ni], b = s2[ni];
            a += __shfl_xor(a, 16); a += __shfl_xor(a, 32);
            b += __shfl_xor(b, 16); b += __shfl_xor(b, 32);
            if (l < 16) {
                atomicAdd(&bns[cols[ni]], a);
                atomicAdd(&bns[256 + cols[ni]], b);
            }
        }
    }

    // ---- manual grid barrier (all 784 blocks co-resident) ----
    __syncthreads();                 // drains this block's atomics (vmcnt)
    if (threadIdx.x == 0) {
        __threadfence();
        __hip_atomic_fetch_add(bar, 1u, __ATOMIC_ACQ_REL, __HIP_MEMORY_SCOPE_AGENT);
        while (__hip_atomic_load(bar, __ATOMIC_ACQUIRE, __HIP_MEMORY_SCOPE_AGENT)
               < (unsigned int)GRIDB) {
            __builtin_amdgcn_s_sleep(8);
        }
    }
    __syncthreads();

    if (active) {
        const float inv_m = 1.f / (float)M_REAL;
        float sc[4], sh[4];
#pragma unroll
        for (int ni = 0; ni < 4; ++ni) {
            // agent-scope loads: bypass non-coherent L1/L2 path
            float t1 = __hip_atomic_load(&bns[cols[ni]], __ATOMIC_RELAXED,
                                         __HIP_MEMORY_SCOPE_AGENT);
            float t2 = __hip_atomic_load(&bns[256 + cols[ni]], __ATOMIC_RELAXED,
                                         __HIP_MEMORY_SCOPE_AGENT);
            float m1 = t1 * inv_m;
            float var = t2 * inv_m - m1 * m1;
            var = fmaxf(var, 0.f);
            float inv = rsqrtf(var + BN_EPS);
            sc[ni] = gamma[cols[ni]] * inv;
            sh[ni] = beta[cols[ni]] - m1 * sc[ni];
        }
#pragma unroll
        for (int mi = 0; mi < 4; ++mi) {
#pragma unroll
            for (int rg = 0; rg < 4; ++rg) {
                int row = tile_m + wm + mi * 16 + kq * 4 + rg;
                if (row < M_REAL) {
#pragma unroll
                    for (int ni = 0; ni < 4; ++ni) {
                        float r = fmaxf(acc[mi][ni][rg] * sc[ni] + sh[ni], 0.f);
                        if (LAST) outp[(size_t)row * 256 + cols[ni]] = r;
                        else      xn[(size_t)row * 768 + 512 + cols[ni]] = f2bf(r);
                    }
                }
            }
        }
    }
}

// ---------------------------------------------------------------------------
// gather in INPUT space: one wave per dst node; 4-edge unroll.
// buf row (stride S=3D(+64)): [u0 0..D | u1 D..2D | x 2D..3D | t-chunk (l0)]
// u_b[dst] = sum_e (c_b/d) * x_src ; t_b = sum_e c_b/d (layer 0 only)
// ---------------------------------------------------------------------------
template<int D, bool HAST>
__global__ __launch_bounds__(256) void gatheru_k(
    unsigned short* buf, const float* __restrict__ comp,
    const unsigned int* __restrict__ rowptr, const float2* __restrict__ erec)
{
    constexpr int E = D / 64;                 // bf16 elems per lane (2 or 4)
    constexpr int S = 3 * D + (HAST ? 64 : 0);
    __shared__ float scomp[32];
    if (threadIdx.x < 32) scomp[threadIdx.x] = comp[threadIdx.x];
    __syncthreads();
    int node = blockIdx.x * 4 + (threadIdx.x >> 6);
    int lane = threadIdx.x & 63;
    unsigned int p0 = rowptr[node], p1 = rowptr[node + 1];
    const unsigned short* xbase = buf + 2 * D + lane * E;

    float a0[E], a1[E], b0[E], b1[E];
#pragma unroll
    for (int e = 0; e < E; ++e) { a0[e] = a1[e] = b0[e] = b1[e] = 0.f; }
    float t0 = 0.f, t1 = 0.f;

    unsigned int p = p0;
    for (; p + 4 <= p1; p += 4) {
        float2 r[4];
        unsigned short v[4][E];
#pragma unroll
        for (int j = 0; j < 4; ++j) r[j] = erec[p + j];
#pragma unroll
        for (int j = 0; j < 4; ++j) {
            unsigned q = __float_as_uint(r[j].x);
            const unsigned short* s = xbase + (size_t)(q >> 4) * S;
            if (E == 2) { ushort2 t = *(const ushort2*)s; v[j][0] = t.x; v[j][1] = t.y; }
            else        { ushort4 t = *(const ushort4*)s; v[j][0] = t.x; v[j][1] = t.y;
                          v[j][2] = t.z; v[j][3] = t.w; }
        }
#pragma unroll
        for (int j = 0; j < 4; ++j) {
            unsigned q = __float_as_uint(r[j].x);
            float w0 = scomp[(q & 15) * 2] * r[j].y;
            float w1 = scomp[(q & 15) * 2 + 1] * r[j].y;
            if (HAST) { t0 += w0; t1 += w1; }
            float* d0 = (j & 1) ? b0 : a0;
            float* d1 = (j & 1) ? b1 : a1;
#pragma unroll
            for (int e = 0; e < E; ++e) {
                float xv = bf2f(v[j][e]);
                d0[e] += w0 * xv;
                d1[e] += w1 * xv;
            }
        }
    }
    for (; p < p1; ++p) {
        float2 r = erec[p];
        unsigned q = __float_as_uint(r.x);
        const unsigned short* s = xbase + (size_t)(q >> 4) * S;
        unsigned short v[E];
        if (E == 2) { ushort2 t = *(const ushort2*)s; v[0] = t.x; v[1] = t.y; }
        else        { ushort4 t = *(const ushort4*)s; v[0] = t.x; v[1] = t.y;
                      v[2] = t.z; v[3] = t.w; }
        float w0 = scomp[(q & 15) * 2] * r.y;
        float w1 = scomp[(q & 15) * 2 + 1] * r.y;
        if (HAST) { t0 += w0; t1 += w1; }
#pragma unroll
        for (int e = 0; e < E; ++e) {
            float xv = bf2f(v[e]);
            a0[e] += w0 * xv;
            a1[e] += w1 * xv;
        }
    }

    unsigned short* orow = buf + (size_t)node * S;
    if (E == 2) {
        ushort2 o0, o1;
        o0.x = f2bf(a0[0] + b0[0]); o0.y = f2bf(a0[1] + b0[1]);
        o1.x = f2bf(a1[0] + b1[0]); o1.y = f2bf(a1[1] + b1[1]);
        *(ushort2*)(orow + lane * 2) = o0;
        *(ushort2*)(orow + D + lane * 2) = o1;
    } else {
        ushort4 o0, o1;
        o0.x = f2bf(a0[0] + b0[0]); o0.y = f2bf(a0[1] + b0[1]);
        o0.z = f2bf(a0[2] + b0[2]); o0.w = f2bf(a0[3] + b0[3]);
        o1.x = f2bf(a1[0] + b1[0]); o1.y = f2bf(a1[1] + b1[1]);
        o1.z = f2bf(a1[2] + b1[2]); o1.w = f2bf(a1[3] + b1[3]);
        *(ushort4*)(orow + lane * 4) = o0;
        *(ushort4*)(orow + D + lane * 4) = o1;
    }
    if (HAST) {
        unsigned short tv = (lane == 0) ? f2bf(t0) : (lane == 1) ? f2bf(t1) : (unsigned short)0;
        orow[3 * D + lane] = tv;
    }
}

// row L2-normalize emb -> bf16 x0, into axl0 at col offset 256 (stride 448)
__global__ __launch_bounds__(256) void norm_k(const float* __restrict__ emb,
                                              unsigned short* __restrict__ buf)
{
    int node = blockIdx.x * 4 + (threadIdx.x >> 6);
    int lane = threadIdx.x & 63;
    const float2* p = (const float2*)(emb + (size_t)node * 128);
    float2 v = p[lane];
    float ss = v.x * v.x + v.y * v.y;
#pragma unroll
    for (int o = 32; o > 0; o >>= 1) ss += __shfl_xor(ss, o);
    float inv = 1.f / fmaxf(sqrtf(ss), 1e-12f);
    unsigned short* row = buf + (size_t)node * 448 + 256;
    unsigned int pack = (unsigned int)f2bf(v.x * inv) | ((unsigned int)f2bf(v.y * inv) << 16);
    ((unsigned int*)row)[lane] = pack;
}

// zero cnt(800000) cntd(50000) cursor(50000) bns(1536) bar(3)
__global__ void zero_k(unsigned int* __restrict__ cnt, unsigned int* __restrict__ cntd,
                       unsigned int* __restrict__ cursor, float* __restrict__ bns,
                       unsigned int* __restrict__ bar)
{
    int i = blockIdx.x * 256 + threadIdx.x;
    if (i < 800000) cnt[i] = 0u;
    if (i < 50000) { cntd[i] = 0u; cursor[i] = 0u; }
    if (i < 1536) bns[i] = 0.f;
    if (i < 3) bar[i] = 0u;
}

__global__ void cnt_k(const int* __restrict__ ei, const int* __restrict__ et,
                      unsigned int* __restrict__ cnt, unsigned int* __restrict__ cntd)
{
    int e = blockIdx.x * 256 + threadIdx.x;
    if (e >= NEDGE) return;
    int dst = ei[NEDGE + e];
    atomicAdd(&cnt[(size_t)dst * NREL + et[e]], 1u);
    atomicAdd(&cntd[dst], 1u);
}

__global__ __launch_bounds__(SCAN_B) void scan1_k(const unsigned int* __restrict__ cntd,
                                                  unsigned int* __restrict__ partial,
                                                  unsigned int* __restrict__ bsum)
{
    __shared__ unsigned int s[SCAN_B];
    int i = blockIdx.x * SCAN_B + threadIdx.x;
    unsigned int v = (i < NNODES) ? cntd[i] : 0u;
    s[threadIdx.x] = v;
    __syncthreads();
    for (int off = 1; off < SCAN_B; off <<= 1) {
        unsigned int t = (threadIdx.x >= off) ? s[threadIdx.x - off] : 0u;
        __syncthreads();
        s[threadIdx.x] += t;
        __syncthreads();
    }
    if (i < NNODES) partial[i] = s[threadIdx.x];
    if (threadIdx.x == SCAN_B - 1) bsum[blockIdx.x] = s[SCAN_B - 1];
}

__global__ __launch_bounds__(128) void scan2_k(unsigned int* __restrict__ bsum)
{
    __shared__ unsigned int s[128];
    unsigned int v = (threadIdx.x < SCAN_NB) ? bsum[threadIdx.x] : 0u;
    s[threadIdx.x] = v;
    __syncthreads();
    for (int off = 1; off < 128; off <<= 1) {
        unsigned int t = (threadIdx.x >= off) ? s[threadIdx.x - off] : 0u;
        __syncthreads();
        s[threadIdx.x] += t;
        __syncthreads();
    }
    if (threadIdx.x < SCAN_NB) bsum[threadIdx.x] = s[threadIdx.x];
}

__global__ __launch_bounds__(SCAN_B) void scan3_k(const unsigned int* __restrict__ partial,
                                                  const unsigned int* __restrict__ bsum,
                                                  unsigned int* __restrict__ rowptr)
{
    int i = blockIdx.x * SCAN_B + threadIdx.x;
    if (i >= NNODES) return;
    unsigned int off = (blockIdx.x > 0) ? bsum[blockIdx.x - 1] : 0u;
    rowptr[i + 1] = partial[i] + off;
    if (i == 0) rowptr[0] = 0u;
}

__global__ void fill_k(const int* __restrict__ ei, const int* __restrict__ et,
                       const unsigned int* __restrict__ cnt,
                       const unsigned int* __restrict__ rowptr,
                       unsigned int* __restrict__ cursor,
                       float2* __restrict__ erec)
{
    int e = blockIdx.x * 256 + threadIdx.x;
    if (e >= NEDGE) return;
    int dst = ei[NEDGE + e];
    int t = et[e];
    unsigned int c = cnt[(size_t)dst * NREL + t];
    unsigned int pos = rowptr[dst] + atomicAdd(&cursor[dst], 1u);
    float2 r;
    r.x = __uint_as_float(((unsigned)ei[e] << 4) | (unsigned)t);
    r.y = 1.f / (float)(c ? c : 1u);
    erec[pos] = r;
}

// PT[j*128+d] = proj_w[d*768+j]
__global__ __launch_bounds__(128) void pt_k(const float* __restrict__ proj_w,
                                            float* __restrict__ PT)
{
    int j = blockIdx.x, d = threadIdx.x;
    PT[(size_t)j * 128 + d] = proj_w[(size_t)d * 768 + j];
}

// layer-0 folded weights: wTm0[n][448]: [P@B0 | P@B1 | P@R | pb@B0, pb@B1, 0..]
// grid 768 = seg(3) x n(256); 128 threads (d)
__global__ __launch_bounds__(128) void pm_k(
    const float* __restrict__ PT, const float* __restrict__ pb,
    const float* __restrict__ b0, const float* __restrict__ r0,
    const float* __restrict__ bias0,
    unsigned short* __restrict__ wTm0, float* __restrict__ biasM0)
{
    __shared__ float sw[128];
    __shared__ float spb[128];
    __shared__ float red[2];
    int seg = blockIdx.x >> 8;
    int n = blockIdx.x & 255;
    int d = threadIdx.x;
    float acc = 0.f, accb = 0.f;
    for (int ch = 0; ch < 6; ++ch) {
        int j0 = ch * 128;
        __syncthreads();
        int j = j0 + d;
        float wv;
        if (seg == 0)      wv = b0[(size_t)j * 256 + n];
        else if (seg == 1) wv = b0[768 * 256 + (size_t)j * 256 + n];
        else               wv = r0[(size_t)j * 256 + n];
        sw[d] = wv;
        spb[d] = pb[j];
        __syncthreads();
#pragma unroll 8
        for (int jj = 0; jj < 128; ++jj)
            acc += PT[(size_t)(j0 + jj) * 128 + d] * sw[jj];
        accb += spb[d] * sw[d];
    }
    for (int o = 32; o > 0; o >>= 1) accb += __shfl_xor(accb, o);
    if ((d & 63) == 0) red[d >> 6] = accb;
    __syncthreads();
    float tb = red[0] + red[1];
    wTm0[(size_t)n * 448 + seg * 128 + d] = f2bf(acc);
    if (seg == 0) { if (d == 0) wTm0[(size_t)n * 448 + 384] = f2bf(tb); }
    else if (seg == 1) { if (d == 0) wTm0[(size_t)n * 448 + 385] = f2bf(tb); }
    else {
        if (d == 0) biasM0[n] = tb + bias0[n];
        if (d >= 2 && d < 64) wTm0[(size_t)n * 448 + 384 + d] = 0;
    }
}

// layers 1/2: wTm[n][768] = [B0 | B1 | R] rows; + biasM fills
__global__ __launch_bounds__(256) void prep_k(
    const float* __restrict__ b1, const float* __restrict__ r1, const float* __restrict__ bias1,
    const float* __restrict__ b2, const float* __restrict__ r2, const float* __restrict__ bias2,
    unsigned short* __restrict__ wTm1, unsigned short* __restrict__ wTm2,
    float* __restrict__ biasM1, float* __restrict__ biasM2)
{
    int b = blockIdx.x;
    int n = threadIdx.x;
    if (b < 1536) {
        int layer = b / 768;
        int rem = b % 768;
        int seg = rem / 256;
        int k = rem % 256;
        const float* bb = layer ? b2 : b1;
        const float* rr = layer ? r2 : r1;
        const float* in = (seg < 2) ? (bb + (size_t)seg * 256 * 256) : rr;
        unsigned short* out = layer ? wTm2 : wTm1;
        out[(size_t)n * 768 + seg * 256 + k] = f2bf(in[(size_t)k * 256 + n]);
    } else {
        int layer = b - 1536;
        float* bm = layer ? biasM2 : biasM1;
        const float* bs = layer ? bias2 : bias1;
        bm[n] = bs[n];
    }
}

extern "C" void kernel_launch(void* const* d_in, const int* in_sizes, int n_in,
                              void* d_out, int out_size, void* d_ws, size_t ws_size,
                              hipStream_t stream)
{
    const int*   edge_index = (const int*)d_in[0];
    const int*   edge_type  = (const int*)d_in[1];
    const float* emb    = (const float*)d_in[2];
    const float* proj_w = (const float*)d_in[3];
    const float* proj_b = (const float*)d_in[4];
    const float* comp[3]  = {(const float*)d_in[5],  (const float*)d_in[11], (const float*)d_in[17]};
    const float* bases[3] = {(const float*)d_in[6],  (const float*)d_in[12], (const float*)d_in[18]};
    const float* root[3]  = {(const float*)d_in[7],  (const float*)d_in[13], (const float*)d_in[19]};
    const float* biasp[3] = {(const float*)d_in[8],  (const float*)d_in[14], (const float*)d_in[20]};
    const float* gamma[3] = {(const float*)d_in[9],  (const float*)d_in[15], (const float*)d_in[21]};
    const float* beta[3]  = {(const float*)d_in[10], (const float*)d_in[16], (const float*)d_in[22]};

    char* ws = (char*)d_ws;
    size_t off = 0;
    auto alloc = [&](size_t bytes) -> char* {
        char* p = ws + off;
        off = (off + bytes + 255) & ~(size_t)255;
        return p;
    };

    unsigned short* axl0 = (unsigned short*)alloc((size_t)NNODES * 448 * 2);
    unsigned short* axl1 = (unsigned short*)alloc((size_t)NNODES * 768 * 2);
    unsigned short* axl2 = (unsigned short*)alloc((size_t)NNODES * 768 * 2);
    unsigned int*   cnt  = (unsigned int*)alloc((size_t)NNODES * NREL * 4);
    unsigned int*   cntd = (unsigned int*)alloc((size_t)NNODES * 4);
    unsigned int*   rowptr = (unsigned int*)alloc((size_t)(NNODES + 1) * 4);
    unsigned int*   cursor = (unsigned int*)alloc((size_t)NNODES * 4);
    unsigned int*   partial = (unsigned int*)alloc((size_t)NNODES * 4);
    unsigned int*   bsum = (unsigned int*)alloc(128 * 4);
    float2*         erec = (float2*)alloc((size_t)NEDGE * 8);
    float*          PT   = (float*)alloc((size_t)768 * 128 * 4);
    unsigned short* wTm0 = (unsigned short*)alloc((size_t)256 * 448 * 2);
    unsigned short* wTm1 = (unsigned short*)alloc((size_t)256 * 768 * 2);
    unsigned short* wTm2 = (unsigned short*)alloc((size_t)256 * 768 * 2);
    float* biasM = (float*)alloc(3 * 256 * 4);
    float* bns   = (float*)alloc(3 * 512 * 4);
    unsigned int* bar = (unsigned int*)alloc(3 * 4);

    zero_k<<<3125, 256, 0, stream>>>(cnt, cntd, cursor, bns, bar);
    norm_k<<<NNODES / 4, 256, 0, stream>>>(emb, axl0);
    cnt_k<<<(NEDGE + 255) / 256, 256, 0, stream>>>(edge_index, edge_type, cnt, cntd);
    scan1_k<<<SCAN_NB, SCAN_B, 0, stream>>>(cntd, partial, bsum);
    scan2_k<<<1, 128, 0, stream>>>(bsum);
    scan3_k<<<SCAN_NB, SCAN_B, 0, stream>>>(partial, bsum, rowptr);
    fill_k<<<(NEDGE + 255) / 256, 256, 0, stream>>>(edge_index, edge_type, cnt, rowptr,
                                                    cursor, erec);

    pt_k<<<768, 128, 0, stream>>>(proj_w, PT);
    pm_k<<<768, 128, 0, stream>>>(PT, proj_b, bases[0], root[0], biasp[0], wTm0, biasM);
    prep_k<<<1538, 256, 0, stream>>>(bases[1], root[1], biasp[1],
                                     bases[2], root[2], biasp[2],
                                     wTm1, wTm2, biasM + 256, biasM + 512);

    // ---- layer 0 (D=128, K=448 with t-chunk) ----
    gatheru_k<128, true><<<NNODES / 4, 256, 0, stream>>>(axl0, comp[0], rowptr, erec);
    gemmf_k<448, false><<<GRIDB, 256, 0, stream>>>(axl0, wTm0, biasM, bns,
                                                   gamma[0], beta[0], axl1, nullptr, bar);

    // ---- layer 1 (D=256, K=768) ----
    gatheru_k<256, false><<<NNODES / 4, 256, 0, stream>>>(axl1, comp[1], rowptr, erec);
    gemmf_k<768, false><<<GRIDB, 256, 0, stream>>>(axl1, wTm1, biasM + 256, bns + 512,
                                                   gamma[1], beta[1], axl2, nullptr, bar + 1);

    // ---- layer 2 (D=256, K=768) ----
    gatheru_k<256, false><<<NNODES / 4, 256, 0, stream>>>(axl2, comp[2], rowptr, erec);
    gemmf_k<768, true><<<GRIDB, 256, 0, stream>>>(axl2, wTm2, biasM + 512, bns + 1024,
                                                  gamma[2], beta[2], nullptr, (float*)d_out, bar + 2);
}

// Round 3
// 816.986 us; speedup vs baseline: 1.2148x; 1.2148x over previous
//
#include <hip/hip_runtime.h>
#include <hip/hip_bf16.h>

#define NNODES 50000
#define NREL   16
#define NEDGE  400000
#define BN_EPS 1e-5f
#define M_REAL NNODES
#define M_TILES 391            /* ceil(50000/128) */
#define RPX    49              /* ceil(391/8) row-blocks per XCD */
#define GRIDB  (8 * RPX * 2)   /* 784 blocks; 4 blocks/CU capacity = 1024 */
#define SCAN_B 512
#define SCAN_NB ((NNODES + SCAN_B - 1) / SCAN_B)   /* 98 */

typedef __attribute__((ext_vector_type(8))) short short8;
typedef __attribute__((ext_vector_type(4))) float f4;

__device__ __forceinline__ float bf2f(unsigned short u) {
    union { unsigned int i; float f; } x; x.i = ((unsigned int)u) << 16; return x.f;
}
__device__ __forceinline__ unsigned short f2bf(float f) {
    __hip_bfloat16 h = __float2bfloat16(f);
    union { __hip_bfloat16 h; unsigned short u; } x; x.h = h; return x.u;
}

__device__ __forceinline__ void g2l16(const unsigned short* g, unsigned short* l) {
    __builtin_amdgcn_global_load_lds(
        (const __attribute__((address_space(1))) unsigned int*)g,
        (__attribute__((address_space(3))) unsigned int*)l,
        16, 0, 0);
}

// ---------------------------------------------------------------------------
// FUSED GEMM + BN + relu with manual grid barrier, LDS-stash epilogue.
// Key change vs R2: acc does NOT live across the barrier. After the K-loop the
// biased tile is rounded to bf16 and stashed into the (dead) As/Bs LDS region
// (exactly 32KB) with XOR swizzle c^=(r&7)<<3 for conflict-free b128 readback.
// Live-across-barrier register state ~10 regs -> no spill at the 128-reg cap
// that __launch_bounds__(256,4) imposes (which guarantees 4 blocks/CU
// co-residency = 1024 slots >= 784 blocks, making the barrier deadlock-free).
// ---------------------------------------------------------------------------
template<int K, bool LAST>
__global__ __launch_bounds__(256, 4) void gemmf_k(
    const unsigned short* __restrict__ A,
    const unsigned short* __restrict__ WT,
    const float* __restrict__ bias,
    float* __restrict__ bns,
    const float* __restrict__ gamma,
    const float* __restrict__ beta,
    unsigned short* __restrict__ xn,
    float* __restrict__ outp,
    unsigned int* __restrict__ bar)
{
    const int lin = blockIdx.x;
    const int xcd = lin & 7;
    const int idx = lin >> 3;
    const int row_blk = xcd * RPX + (idx >> 1);
    const int nt = idx & 1;
    const bool active = (row_blk < M_TILES);
    const int tile_m = row_blk * 128;
    const int tile_n = nt * 128;

    // As = lds[0..8191], Bs = lds[8192..16383]; after K-loop the whole 16384
    // shorts become the bf16 y-stash [128][128] (XOR-swizzled).
    __shared__ unsigned short lds[128 * 128];
    __shared__ float scsh[256];

    const int w = threadIdx.x >> 6;
    const int l = threadIdx.x & 63;
    const int lm = l & 15;
    const int kq = l >> 4;
    const int wm = (w & 1) << 6;
    const int wn = (w >> 1) << 6;

    if (active) {
        unsigned short* As = lds;
        unsigned short* Bs = lds + 8192;
        const int lrow = l >> 3;
        const int chunk = ((l & 7) + 8 - lrow) & 7;

        // u32 element offsets (A/WT bases stay in SGPRs -> saddr form)
        unsigned aof[4], bof[4];
#pragma unroll
        for (int it = 0; it < 4; ++it) {
            int rt = it * 32 + w * 8 + lrow;
            int rg = tile_m + rt; if (rg >= M_REAL) rg = M_REAL - 1;
            aof[it] = (unsigned)rg * (unsigned)K + (unsigned)(chunk * 8);
            bof[it] = (unsigned)(tile_n + rt) * (unsigned)K + (unsigned)(chunk * 8);
        }

        unsigned aoff[4], boff[4];
#pragma unroll
        for (int mi = 0; mi < 4; ++mi) {
            aoff[mi] = (unsigned)((wm + mi * 16 + lm) * 128 + (((kq + lm) & 7) << 4));
            boff[mi] = (unsigned)((wn + mi * 16 + lm) * 128 + (((kq + lm) & 7) << 4));
        }

        f4 acc[4][4];
#pragma unroll
        for (int mi = 0; mi < 4; ++mi)
#pragma unroll
            for (int ni = 0; ni < 4; ++ni) acc[mi][ni] = (f4){0.f, 0.f, 0.f, 0.f};

        for (int kc = 0; kc < K; kc += 64) {
#pragma unroll
            for (int it = 0; it < 4; ++it) {
                g2l16(A + aof[it] + kc, As + (it * 32 + w * 8) * 64);
                g2l16(WT + bof[it] + kc, Bs + (it * 32 + w * 8) * 64);
            }
            __syncthreads();
#pragma unroll
            for (int kh = 0; kh < 2; ++kh) {
                const unsigned x = kh << 6;
                short8 af[4], bfr[4];
#pragma unroll
                for (int mi = 0; mi < 4; ++mi)
                    af[mi] = *(const short8*)((const char*)As + (aoff[mi] ^ x));
#pragma unroll
                for (int ni = 0; ni < 4; ++ni)
                    bfr[ni] = *(const short8*)((const char*)Bs + (boff[ni] ^ x));
#pragma unroll
                for (int mi = 0; mi < 4; ++mi)
#pragma unroll
                    for (int ni = 0; ni < 4; ++ni)
                        acc[mi][ni] = __builtin_amdgcn_mfma_f32_16x16x32_bf16(
                            af[mi], bfr[ni], acc[mi][ni], 0, 0, 0);
            }
            __syncthreads();
        }

        // epilogue A: bias add, stats, bf16 stash into lds (As/Bs now dead)
        float bv[4];
#pragma unroll
        for (int ni = 0; ni < 4; ++ni) bv[ni] = bias[tile_n + wn + ni * 16 + lm];
        float s1[4] = {0.f, 0.f, 0.f, 0.f}, s2[4] = {0.f, 0.f, 0.f, 0.f};
#pragma unroll
        for (int mi = 0; mi < 4; ++mi) {
#pragma unroll
            for (int rg = 0; rg < 4; ++rg) {
                int rloc = wm + mi * 16 + kq * 4 + rg;
                bool live = (tile_m + rloc) < M_REAL;
                int xr = (rloc & 7) << 3;
#pragma unroll
                for (int ni = 0; ni < 4; ++ni) {
                    float v = acc[mi][ni][rg] + bv[ni];
                    lds[rloc * 128 + ((wn + ni * 16 + lm) ^ xr)] = f2bf(v);
                    if (live) { s1[ni] += v; s2[ni] += v * v; }
                }
            }
        }
#pragma unroll
        for (int ni = 0; ni < 4; ++ni) {
            float a = s1[ni], b = s2[ni];
            a += __shfl_xor(a, 16); a += __shfl_xor(a, 32);
            b += __shfl_xor(b, 16); b += __shfl_xor(b, 32);
            if (l < 16) {
                int c = tile_n + wn + ni * 16 + lm;
                atomicAdd(&bns[c], a);
                atomicAdd(&bns[256 + c], b);
            }
        }
    }

    // ---- manual grid barrier (all 784 blocks co-resident at 4/CU) ----
    __syncthreads();                 // drains this block's atomics + LDS writes
    if (threadIdx.x == 0) {
        __threadfence();
        __hip_atomic_fetch_add(bar, 1u, __ATOMIC_ACQ_REL, __HIP_MEMORY_SCOPE_AGENT);
        while (__hip_atomic_load(bar, __ATOMIC_ACQUIRE, __HIP_MEMORY_SCOPE_AGENT)
               < (unsigned int)GRIDB) {
            __builtin_amdgcn_s_sleep(8);
        }
    }
    __syncthreads();

    if (active) {
        // per-column BN scale/shift into LDS (agent-scope loads of bns)
        if (threadIdx.x < 128) {
            const float inv_m = 1.f / (float)M_REAL;
            int c = tile_n + threadIdx.x;
            float t1 = __hip_atomic_load(&bns[c], __ATOMIC_RELAXED,
                                         __HIP_MEMORY_SCOPE_AGENT);
            float t2 = __hip_atomic_load(&bns[256 + c], __ATOMIC_RELAXED,
                                         __HIP_MEMORY_SCOPE_AGENT);
            float m1 = t1 * inv_m;
            float var = fmaxf(t2 * inv_m - m1 * m1, 0.f);
            float inv = rsqrtf(var + BN_EPS);
            float sc = gamma[c] * inv;
            scsh[threadIdx.x] = sc;
            scsh[128 + threadIdx.x] = beta[c] - m1 * sc;
        }
        __syncthreads();

        // apply: thread t -> row r=t>>1, col half (t&1)*64..+63; vectorized
        const int r = threadIdx.x >> 1;
        const int half = threadIdx.x & 1;
        const int grow = tile_m + r;
        if (grow < M_REAL) {
            const int xr = (r & 7) << 3;
#pragma unroll
            for (int ch = 0; ch < 8; ++ch) {
                int c0 = half * 64 + ch * 8;
                short8 sv = *(const short8*)&lds[r * 128 + (c0 ^ xr)];
                f4 sca = *(const f4*)&scsh[c0];
                f4 scb = *(const f4*)&scsh[c0 + 4];
                f4 sha = *(const f4*)&scsh[128 + c0];
                f4 shb = *(const f4*)&scsh[128 + c0 + 4];
                float o0 = fmaxf(bf2f((unsigned short)sv[0]) * sca.x + sha.x, 0.f);
                float o1 = fmaxf(bf2f((unsigned short)sv[1]) * sca.y + sha.y, 0.f);
                float o2 = fmaxf(bf2f((unsigned short)sv[2]) * sca.z + sha.z, 0.f);
                float o3 = fmaxf(bf2f((unsigned short)sv[3]) * sca.w + sha.w, 0.f);
                float o4 = fmaxf(bf2f((unsigned short)sv[4]) * scb.x + shb.x, 0.f);
                float o5 = fmaxf(bf2f((unsigned short)sv[5]) * scb.y + shb.y, 0.f);
                float o6 = fmaxf(bf2f((unsigned short)sv[6]) * scb.z + shb.z, 0.f);
                float o7 = fmaxf(bf2f((unsigned short)sv[7]) * scb.w + shb.w, 0.f);
                if (LAST) {
                    f4 w0 = {o0, o1, o2, o3};
                    f4 w1 = {o4, o5, o6, o7};
                    float* dst = outp + (size_t)grow * 256 + tile_n + c0;
                    *(f4*)dst = w0;
                    *(f4*)(dst + 4) = w1;
                } else {
                    short8 u;
                    u[0] = (short)f2bf(o0); u[1] = (short)f2bf(o1);
                    u[2] = (short)f2bf(o2); u[3] = (short)f2bf(o3);
                    u[4] = (short)f2bf(o4); u[5] = (short)f2bf(o5);
                    u[6] = (short)f2bf(o6); u[7] = (short)f2bf(o7);
                    *(short8*)(xn + (size_t)grow * 768 + 512 + tile_n + c0) = u;
                }
            }
        }
    }
}

// ---------------------------------------------------------------------------
// gather in INPUT space: one wave per dst node; 4-edge unroll.
// buf row (stride S=3D(+64)): [u0 0..D | u1 D..2D | x 2D..3D | t-chunk (l0)]
// u_b[dst] = sum_e (c_b/d) * x_src ; t_b = sum_e c_b/d (layer 0 only)
// ---------------------------------------------------------------------------
template<int D, bool HAST>
__global__ __launch_bounds__(256) void gatheru_k(
    unsigned short* buf, const float* __restrict__ comp,
    const unsigned int* __restrict__ rowptr, const float2* __restrict__ erec)
{
    constexpr int E = D / 64;                 // bf16 elems per lane (2 or 4)
    constexpr int S = 3 * D + (HAST ? 64 : 0);
    __shared__ float scomp[32];
    if (threadIdx.x < 32) scomp[threadIdx.x] = comp[threadIdx.x];
    __syncthreads();
    int node = blockIdx.x * 4 + (threadIdx.x >> 6);
    int lane = threadIdx.x & 63;
    unsigned int p0 = rowptr[node], p1 = rowptr[node + 1];
    const unsigned short* xbase = buf + 2 * D + lane * E;

    float a0[E], a1[E], b0[E], b1[E];
#pragma unroll
    for (int e = 0; e < E; ++e) { a0[e] = a1[e] = b0[e] = b1[e] = 0.f; }
    float t0 = 0.f, t1 = 0.f;

    unsigned int p = p0;
    for (; p + 4 <= p1; p += 4) {
        float2 r[4];
        unsigned short v[4][E];
#pragma unroll
        for (int j = 0; j < 4; ++j) r[j] = erec[p + j];
#pragma unroll
        for (int j = 0; j < 4; ++j) {
            unsigned q = __float_as_uint(r[j].x);
            const unsigned short* s = xbase + (size_t)(q >> 4) * S;
            if (E == 2) { ushort2 t = *(const ushort2*)s; v[j][0] = t.x; v[j][1] = t.y; }
            else        { ushort4 t = *(const ushort4*)s; v[j][0] = t.x; v[j][1] = t.y;
                          v[j][2] = t.z; v[j][3] = t.w; }
        }
#pragma unroll
        for (int j = 0; j < 4; ++j) {
            unsigned q = __float_as_uint(r[j].x);
            float w0 = scomp[(q & 15) * 2] * r[j].y;
            float w1 = scomp[(q & 15) * 2 + 1] * r[j].y;
            if (HAST) { t0 += w0; t1 += w1; }
            float* d0 = (j & 1) ? b0 : a0;
            float* d1 = (j & 1) ? b1 : a1;
#pragma unroll
            for (int e = 0; e < E; ++e) {
                float xv = bf2f(v[j][e]);
                d0[e] += w0 * xv;
                d1[e] += w1 * xv;
            }
        }
    }
    for (; p < p1; ++p) {
        float2 r = erec[p];
        unsigned q = __float_as_uint(r.x);
        const unsigned short* s = xbase + (size_t)(q >> 4) * S;
        unsigned short v[E];
        if (E == 2) { ushort2 t = *(const ushort2*)s; v[0] = t.x; v[1] = t.y; }
        else        { ushort4 t = *(const ushort4*)s; v[0] = t.x; v[1] = t.y;
                      v[2] = t.z; v[3] = t.w; }
        float w0 = scomp[(q & 15) * 2] * r.y;
        float w1 = scomp[(q & 15) * 2 + 1] * r.y;
        if (HAST) { t0 += w0; t1 += w1; }
#pragma unroll
        for (int e = 0; e < E; ++e) {
            float xv = bf2f(v[e]);
            a0[e] += w0 * xv;
            a1[e] += w1 * xv;
        }
    }

    unsigned short* orow = buf + (size_t)node * S;
    if (E == 2) {
        ushort2 o0, o1;
        o0.x = f2bf(a0[0] + b0[0]); o0.y = f2bf(a0[1] + b0[1]);
        o1.x = f2bf(a1[0] + b1[0]); o1.y = f2bf(a1[1] + b1[1]);
        *(ushort2*)(orow + lane * 2) = o0;
        *(ushort2*)(orow + D + lane * 2) = o1;
    } else {
        ushort4 o0, o1;
        o0.x = f2bf(a0[0] + b0[0]); o0.y = f2bf(a0[1] + b0[1]);
        o0.z = f2bf(a0[2] + b0[2]); o0.w = f2bf(a0[3] + b0[3]);
        o1.x = f2bf(a1[0] + b1[0]); o1.y = f2bf(a1[1] + b1[1]);
        o1.z = f2bf(a1[2] + b1[2]); o1.w = f2bf(a1[3] + b1[3]);
        *(ushort4*)(orow + lane * 4) = o0;
        *(ushort4*)(orow + D + lane * 4) = o1;
    }
    if (HAST) {
        unsigned short tv = (lane == 0) ? f2bf(t0) : (lane == 1) ? f2bf(t1) : (unsigned short)0;
        orow[3 * D + lane] = tv;
    }
}

// row L2-normalize emb -> bf16 x0, into axl0 at col offset 256 (stride 448)
__global__ __launch_bounds__(256) void norm_k(const float* __restrict__ emb,
                                              unsigned short* __restrict__ buf)
{
    int node = blockIdx.x * 4 + (threadIdx.x >> 6);
    int lane = threadIdx.x & 63;
    const float2* p = (const float2*)(emb + (size_t)node * 128);
    float2 v = p[lane];
    float ss = v.x * v.x + v.y * v.y;
#pragma unroll
    for (int o = 32; o > 0; o >>= 1) ss += __shfl_xor(ss, o);
    float inv = 1.f / fmaxf(sqrtf(ss), 1e-12f);
    unsigned short* row = buf + (size_t)node * 448 + 256;
    unsigned int pack = (unsigned int)f2bf(v.x * inv) | ((unsigned int)f2bf(v.y * inv) << 16);
    ((unsigned int*)row)[lane] = pack;
}

// zero cnt(800000) cntd(50000) cursor(50000) bns(1536) bar(3)
__global__ void zero_k(unsigned int* __restrict__ cnt, unsigned int* __restrict__ cntd,
                       unsigned int* __restrict__ cursor, float* __restrict__ bns,
                       unsigned int* __restrict__ bar)
{
    int i = blockIdx.x * 256 + threadIdx.x;
    if (i < 800000) cnt[i] = 0u;
    if (i < 50000) { cntd[i] = 0u; cursor[i] = 0u; }
    if (i < 1536) bns[i] = 0.f;
    if (i < 3) bar[i] = 0u;
}

__global__ void cnt_k(const int* __restrict__ ei, const int* __restrict__ et,
                      unsigned int* __restrict__ cnt, unsigned int* __restrict__ cntd)
{
    int e = blockIdx.x * 256 + threadIdx.x;
    if (e >= NEDGE) return;
    int dst = ei[NEDGE + e];
    atomicAdd(&cnt[(size_t)dst * NREL + et[e]], 1u);
    atomicAdd(&cntd[dst], 1u);
}

__global__ __launch_bounds__(SCAN_B) void scan1_k(const unsigned int* __restrict__ cntd,
                                                  unsigned int* __restrict__ partial,
                                                  unsigned int* __restrict__ bsum)
{
    __shared__ unsigned int s[SCAN_B];
    int i = blockIdx.x * SCAN_B + threadIdx.x;
    unsigned int v = (i < NNODES) ? cntd[i] : 0u;
    s[threadIdx.x] = v;
    __syncthreads();
    for (int off = 1; off < SCAN_B; off <<= 1) {
        unsigned int t = (threadIdx.x >= off) ? s[threadIdx.x - off] : 0u;
        __syncthreads();
        s[threadIdx.x] += t;
        __syncthreads();
    }
    if (i < NNODES) partial[i] = s[threadIdx.x];
    if (threadIdx.x == SCAN_B - 1) bsum[blockIdx.x] = s[SCAN_B - 1];
}

__global__ __launch_bounds__(128) void scan2_k(unsigned int* __restrict__ bsum)
{
    __shared__ unsigned int s[128];
    unsigned int v = (threadIdx.x < SCAN_NB) ? bsum[threadIdx.x] : 0u;
    s[threadIdx.x] = v;
    __syncthreads();
    for (int off = 1; off < 128; off <<= 1) {
        unsigned int t = (threadIdx.x >= off) ? s[threadIdx.x - off] : 0u;
        __syncthreads();
        s[threadIdx.x] += t;
        __syncthreads();
    }
    if (threadIdx.x < SCAN_NB) bsum[threadIdx.x] = s[threadIdx.x];
}

__global__ __launch_bounds__(SCAN_B) void scan3_k(const unsigned int* __restrict__ partial,
                                                  const unsigned int* __restrict__ bsum,
                                                  unsigned int* __restrict__ rowptr)
{
    int i = blockIdx.x * SCAN_B + threadIdx.x;
    if (i >= NNODES) return;
    unsigned int off = (blockIdx.x > 0) ? bsum[blockIdx.x - 1] : 0u;
    rowptr[i + 1] = partial[i] + off;
    if (i == 0) rowptr[0] = 0u;
}

__global__ void fill_k(const int* __restrict__ ei, const int* __restrict__ et,
                       const unsigned int* __restrict__ cnt,
                       const unsigned int* __restrict__ rowptr,
                       unsigned int* __restrict__ cursor,
                       float2* __restrict__ erec)
{
    int e = blockIdx.x * 256 + threadIdx.x;
    if (e >= NEDGE) return;
    int dst = ei[NEDGE + e];
    int t = et[e];
    unsigned int c = cnt[(size_t)dst * NREL + t];
    unsigned int pos = rowptr[dst] + atomicAdd(&cursor[dst], 1u);
    float2 r;
    r.x = __uint_as_float(((unsigned)ei[e] << 4) | (unsigned)t);
    r.y = 1.f / (float)(c ? c : 1u);
    erec[pos] = r;
}

// PT[j*128+d] = proj_w[d*768+j]
__global__ __launch_bounds__(128) void pt_k(const float* __restrict__ proj_w,
                                            float* __restrict__ PT)
{
    int j = blockIdx.x, d = threadIdx.x;
    PT[(size_t)j * 128 + d] = proj_w[(size_t)d * 768 + j];
}

// layer-0 folded weights: wTm0[n][448]: [P@B0 | P@B1 | P@R | pb@B0, pb@B1, 0..]
// grid 768 = seg(3) x n(256); 128 threads (d)
__global__ __launch_bounds__(128) void pm_k(
    const float* __restrict__ PT, const float* __restrict__ pb,
    const float* __restrict__ b0, const float* __restrict__ r0,
    const float* __restrict__ bias0,
    unsigned short* __restrict__ wTm0, float* __restrict__ biasM0)
{
    __shared__ float sw[128];
    __shared__ float spb[128];
    __shared__ float red[2];
    int seg = blockIdx.x >> 8;
    int n = blockIdx.x & 255;
    int d = threadIdx.x;
    float acc = 0.f, accb = 0.f;
    for (int ch = 0; ch < 6; ++ch) {
        int j0 = ch * 128;
        __syncthreads();
        int j = j0 + d;
        float wv;
        if (seg == 0)      wv = b0[(size_t)j * 256 + n];
        else if (seg == 1) wv = b0[768 * 256 + (size_t)j * 256 + n];
        else               wv = r0[(size_t)j * 256 + n];
        sw[d] = wv;
        spb[d] = pb[j];
        __syncthreads();
#pragma unroll 8
        for (int jj = 0; jj < 128; ++jj)
            acc += PT[(size_t)(j0 + jj) * 128 + d] * sw[jj];
        accb += spb[d] * sw[d];
    }
    for (int o = 32; o > 0; o >>= 1) accb += __shfl_xor(accb, o);
    if ((d & 63) == 0) red[d >> 6] = accb;
    __syncthreads();
    float tb = red[0] + red[1];
    wTm0[(size_t)n * 448 + seg * 128 + d] = f2bf(acc);
    if (seg == 0) { if (d == 0) wTm0[(size_t)n * 448 + 384] = f2bf(tb); }
    else if (seg == 1) { if (d == 0) wTm0[(size_t)n * 448 + 385] = f2bf(tb); }
    else {
        if (d == 0) biasM0[n] = tb + bias0[n];
        if (d >= 2 && d < 64) wTm0[(size_t)n * 448 + 384 + d] = 0;
    }
}

// layers 1/2: wTm[n][768] = [B0 | B1 | R] rows; + biasM fills
__global__ __launch_bounds__(256) void prep_k(
    const float* __restrict__ b1, const float* __restrict__ r1, const float* __restrict__ bias1,
    const float* __restrict__ b2, const float* __restrict__ r2, const float* __restrict__ bias2,
    unsigned short* __restrict__ wTm1, unsigned short* __restrict__ wTm2,
    float* __restrict__ biasM1, float* __restrict__ biasM2)
{
    int b = blockIdx.x;
    int n = threadIdx.x;
    if (b < 1536) {
        int layer = b / 768;
        int rem = b % 768;
        int seg = rem / 256;
        int k = rem % 256;
        const float* bb = layer ? b2 : b1;
        const float* rr = layer ? r2 : r1;
        const float* in = (seg < 2) ? (bb + (size_t)seg * 256 * 256) : rr;
        unsigned short* out = layer ? wTm2 : wTm1;
        out[(size_t)n * 768 + seg * 256 + k] = f2bf(in[(size_t)k * 256 + n]);
    } else {
        int layer = b - 1536;
        float* bm = layer ? biasM2 : biasM1;
        const float* bs = layer ? bias2 : bias1;
        bm[n] = bs[n];
    }
}

extern "C" void kernel_launch(void* const* d_in, const int* in_sizes, int n_in,
                              void* d_out, int out_size, void* d_ws, size_t ws_size,
                              hipStream_t stream)
{
    const int*   edge_index = (const int*)d_in[0];
    const int*   edge_type  = (const int*)d_in[1];
    const float* emb    = (const float*)d_in[2];
    const float* proj_w = (const float*)d_in[3];
    const float* proj_b = (const float*)d_in[4];
    const float* comp[3]  = {(const float*)d_in[5],  (const float*)d_in[11], (const float*)d_in[17]};
    const float* bases[3] = {(const float*)d_in[6],  (const float*)d_in[12], (const float*)d_in[18]};
    const float* root[3]  = {(const float*)d_in[7],  (const float*)d_in[13], (const float*)d_in[19]};
    const float* biasp[3] = {(const float*)d_in[8],  (const float*)d_in[14], (const float*)d_in[20]};
    const float* gamma[3] = {(const float*)d_in[9],  (const float*)d_in[15], (const float*)d_in[21]};
    const float* beta[3]  = {(const float*)d_in[10], (const float*)d_in[16], (const float*)d_in[22]};

    char* ws = (char*)d_ws;
    size_t off = 0;
    auto alloc = [&](size_t bytes) -> char* {
        char* p = ws + off;
        off = (off + bytes + 255) & ~(size_t)255;
        return p;
    };

    unsigned short* axl0 = (unsigned short*)alloc((size_t)NNODES * 448 * 2);
    unsigned short* axl1 = (unsigned short*)alloc((size_t)NNODES * 768 * 2);
    unsigned short* axl2 = (unsigned short*)alloc((size_t)NNODES * 768 * 2);
    unsigned int*   cnt  = (unsigned int*)alloc((size_t)NNODES * NREL * 4);
    unsigned int*   cntd = (unsigned int*)alloc((size_t)NNODES * 4);
    unsigned int*   rowptr = (unsigned int*)alloc((size_t)(NNODES + 1) * 4);
    unsigned int*   cursor = (unsigned int*)alloc((size_t)NNODES * 4);
    unsigned int*   partial = (unsigned int*)alloc((size_t)NNODES * 4);
    unsigned int*   bsum = (unsigned int*)alloc(128 * 4);
    float2*         erec = (float2*)alloc((size_t)NEDGE * 8);
    float*          PT   = (float*)alloc((size_t)768 * 128 * 4);
    unsigned short* wTm0 = (unsigned short*)alloc((size_t)256 * 448 * 2);
    unsigned short* wTm1 = (unsigned short*)alloc((size_t)256 * 768 * 2);
    unsigned short* wTm2 = (unsigned short*)alloc((size_t)256 * 768 * 2);
    float* biasM = (float*)alloc(3 * 256 * 4);
    float* bns   = (float*)alloc(3 * 512 * 4);
    unsigned int* bar = (unsigned int*)alloc(3 * 4);

    zero_k<<<3125, 256, 0, stream>>>(cnt, cntd, cursor, bns, bar);
    norm_k<<<NNODES / 4, 256, 0, stream>>>(emb, axl0);
    cnt_k<<<(NEDGE + 255) / 256, 256, 0, stream>>>(edge_index, edge_type, cnt, cntd);
    scan1_k<<<SCAN_NB, SCAN_B, 0, stream>>>(cntd, partial, bsum);
    scan2_k<<<1, 128, 0, stream>>>(bsum);
    scan3_k<<<SCAN_NB, SCAN_B, 0, stream>>>(partial, bsum, rowptr);
    fill_k<<<(NEDGE + 255) / 256, 256, 0, stream>>>(edge_index, edge_type, cnt, rowptr,
                                                    cursor, erec);

    pt_k<<<768, 128, 0, stream>>>(proj_w, PT);
    pm_k<<<768, 128, 0, stream>>>(PT, proj_b, bases[0], root[0], biasp[0], wTm0, biasM);
    prep_k<<<1538, 256, 0, stream>>>(bases[1], root[1], biasp[1],
                                     bases[2], root[2], biasp[2],
                                     wTm1, wTm2, biasM + 256, biasM + 512);

    // ---- layer 0 (D=128, K=448 with t-chunk) ----
    gatheru_k<128, true><<<NNODES / 4, 256, 0, stream>>>(axl0, comp[0], rowptr, erec);
    gemmf_k<448, false><<<GRIDB, 256, 0, stream>>>(axl0, wTm0, biasM, bns,
                                                   gamma[0], beta[0], axl1, nullptr, bar);

    // ---- layer 1 (D=256, K=768) ----
    gatheru_k<256, false><<<NNODES / 4, 256, 0, stream>>>(axl1, comp[1], rowptr, erec);
    gemmf_k<768, false><<<GRIDB, 256, 0, stream>>>(axl1, wTm1, biasM + 256, bns + 512,
                                                   gamma[1], beta[1], axl2, nullptr, bar + 1);

    // ---- layer 2 (D=256, K=768) ----
    gatheru_k<256, false><<<NNODES / 4, 256, 0, stream>>>(axl2, comp[2], rowptr, erec);
    gemmf_k<768, true><<<GRIDB, 256, 0, stream>>>(axl2, wTm2, biasM + 512, bns + 1024,
                                                  gamma[2], beta[2], nullptr, (float*)d_out, bar + 2);
}

// Round 4
// 792.238 us; speedup vs baseline: 1.2528x; 1.0312x over previous
//
#include <hip/hip_runtime.h>
#include <hip/hip_bf16.h>

#define NNODES 50000
#define NREL   16
#define NEDGE  400000
#define BN_EPS 1e-5f
#define M_REAL NNODES
#define M_TILES 391            /* ceil(50000/128) */
#define RPX    49              /* ceil(391/8) row-tiles per XCD */
#define GRIDB  512             /* 8 XCD x 64; 2 blocks/CU co-resident = 512 */
#define SCAN_B 512
#define SCAN_NB ((NNODES + SCAN_B - 1) / SCAN_B)   /* 98 */

typedef __attribute__((ext_vector_type(8))) short short8;
typedef __attribute__((ext_vector_type(4))) float f4;

__device__ __forceinline__ float bf2f(unsigned short u) {
    union { unsigned int i; float f; } x; x.i = ((unsigned int)u) << 16; return x.f;
}
__device__ __forceinline__ unsigned short f2bf(float f) {
    __hip_bfloat16 h = __float2bfloat16(f);
    union { __hip_bfloat16 h; unsigned short u; } x; x.h = h; return x.u;
}

__device__ __forceinline__ void g2l16(const unsigned short* g, unsigned short* l) {
    __builtin_amdgcn_global_load_lds(
        (const __attribute__((address_space(1))) unsigned int*)g,
        (__attribute__((address_space(3))) unsigned int*)l,
        16, 0, 0);
}

// ---------------------------------------------------------------------------
// FUSED GEMM + BN + relu, manual grid barrier. R4 change vs R3:
//   tile = 128x256 (full N), grid 512 @ __launch_bounds__(256,2) -> 256
//   regs/wave (no reg starvation: acc f4[4][8]=128 + frags ~48 + addr ~20).
//   2 blocks/CU co-resident (512 slots >= 512 blocks) -> barrier safe.
//   acc survives the barrier in registers; bf16 LDS stash (dead Bs region,
//   one 128-col half at a time) used only to coalesce the global stores.
//   A-tile now fetched once (no nt duplication).
// ---------------------------------------------------------------------------
template<int K, bool LAST>
__global__ __launch_bounds__(256, 2) void gemmf_k(
    const unsigned short* __restrict__ A,
    const unsigned short* __restrict__ WT,
    const float* __restrict__ bias,
    float* __restrict__ bns,
    const float* __restrict__ gamma,
    const float* __restrict__ beta,
    unsigned short* __restrict__ xn,
    float* __restrict__ outp,
    unsigned int* __restrict__ bar)
{
    const int lin = blockIdx.x;
    const int xcd = lin & 7;
    const int idx = lin >> 3;                 // 0..63
    const int row_blk = xcd * RPX + idx;
    const bool active = (idx < RPX) && (row_blk < M_TILES);
    const int tile_m = row_blk * 128;

    // As = lds[0..8191] (128x64), Bs = lds[8192..24575] (256x64).
    // After the K-loop, Bs doubles as the 128x128 bf16 stash per half.
    __shared__ unsigned short lds[24576];
    __shared__ float scsh[512];

    const int w = threadIdx.x >> 6;
    const int l = threadIdx.x & 63;
    const int lm = l & 15;
    const int kq = l >> 4;
    const int wm = (w & 1) << 6;              // 0,64   (row group)
    const int wn = (w >> 1) << 7;             // 0,128  (col group)

    f4 acc[4][8];
#pragma unroll
    for (int mi = 0; mi < 4; ++mi)
#pragma unroll
        for (int ni = 0; ni < 8; ++ni) acc[mi][ni] = (f4){0.f, 0.f, 0.f, 0.f};

    if (active) {
        unsigned short* As = lds;
        unsigned short* Bs = lds + 8192;
        const int lrow = l >> 3;
        const int chunk = ((l & 7) + 8 - lrow) & 7;

        unsigned aof[4], bof[8];
#pragma unroll
        for (int it = 0; it < 4; ++it) {
            int rt = it * 32 + w * 8 + lrow;
            int rg = tile_m + rt; if (rg >= M_REAL) rg = M_REAL - 1;
            aof[it] = (unsigned)rg * (unsigned)K + (unsigned)(chunk * 8);
        }
#pragma unroll
        for (int it = 0; it < 8; ++it) {
            int rt = it * 32 + w * 8 + lrow;
            bof[it] = (unsigned)rt * (unsigned)K + (unsigned)(chunk * 8);
        }

        unsigned aoff[4], boff[8];
#pragma unroll
        for (int mi = 0; mi < 4; ++mi)
            aoff[mi] = (unsigned)((wm + mi * 16 + lm) * 128 + (((kq + lm) & 7) << 4));
#pragma unroll
        for (int ni = 0; ni < 8; ++ni)
            boff[ni] = (unsigned)(16384 + (wn + ni * 16 + lm) * 128 + (((kq + lm) & 7) << 4));

        for (int kc = 0; kc < K; kc += 64) {
#pragma unroll
            for (int it = 0; it < 4; ++it)
                g2l16(A + aof[it] + kc, As + (it * 32 + w * 8) * 64);
#pragma unroll
            for (int it = 0; it < 8; ++it)
                g2l16(WT + bof[it] + kc, Bs + (it * 32 + w * 8) * 64);
            __syncthreads();
#pragma unroll
            for (int kh = 0; kh < 2; ++kh) {
                const unsigned x = kh << 6;
                short8 af[4], bfr[8];
#pragma unroll
                for (int mi = 0; mi < 4; ++mi)
                    af[mi] = *(const short8*)((const char*)lds + (aoff[mi] ^ x));
#pragma unroll
                for (int ni = 0; ni < 8; ++ni)
                    bfr[ni] = *(const short8*)((const char*)lds + (boff[ni] ^ x));
#pragma unroll
                for (int mi = 0; mi < 4; ++mi)
#pragma unroll
                    for (int ni = 0; ni < 8; ++ni)
                        acc[mi][ni] = __builtin_amdgcn_mfma_f32_16x16x32_bf16(
                            af[mi], bfr[ni], acc[mi][ni], 0, 0, 0);
            }
            __syncthreads();
        }

        // bias add in-register + column stats
        float bv[8];
#pragma unroll
        for (int ni = 0; ni < 8; ++ni) bv[ni] = bias[wn + ni * 16 + lm];
        float s1[8], s2[8];
#pragma unroll
        for (int ni = 0; ni < 8; ++ni) { s1[ni] = 0.f; s2[ni] = 0.f; }
#pragma unroll
        for (int mi = 0; mi < 4; ++mi) {
#pragma unroll
            for (int rg = 0; rg < 4; ++rg) {
                int rloc = wm + mi * 16 + kq * 4 + rg;
                bool live = (tile_m + rloc) < M_REAL;
#pragma unroll
                for (int ni = 0; ni < 8; ++ni) {
                    float v = acc[mi][ni][rg] + bv[ni];
                    acc[mi][ni][rg] = v;
                    if (live) { s1[ni] += v; s2[ni] += v * v; }
                }
            }
        }
#pragma unroll
        for (int ni = 0; ni < 8; ++ni) {
            float a = s1[ni], b = s2[ni];
            a += __shfl_xor(a, 16); a += __shfl_xor(a, 32);
            b += __shfl_xor(b, 16); b += __shfl_xor(b, 32);
            if (l < 16) {
                int c = wn + ni * 16 + lm;
                atomicAdd(&bns[c], a);
                atomicAdd(&bns[256 + c], b);
            }
        }
    }

    // ---- manual grid barrier (512 blocks co-resident at 2/CU) ----
    __syncthreads();
    if (threadIdx.x == 0) {
        __threadfence();
        __hip_atomic_fetch_add(bar, 1u, __ATOMIC_ACQ_REL, __HIP_MEMORY_SCOPE_AGENT);
        while (__hip_atomic_load(bar, __ATOMIC_ACQUIRE, __HIP_MEMORY_SCOPE_AGENT)
               < (unsigned int)GRIDB) {
            __builtin_amdgcn_s_sleep(8);
        }
    }
    __syncthreads();

    if (active) {
        // per-column BN scale/shift (agent-scope bns loads), 256 threads x 256 cols
        {
            const float inv_m = 1.f / (float)M_REAL;
            int c = threadIdx.x;
            float t1 = __hip_atomic_load(&bns[c], __ATOMIC_RELAXED,
                                         __HIP_MEMORY_SCOPE_AGENT);
            float t2 = __hip_atomic_load(&bns[256 + c], __ATOMIC_RELAXED,
                                         __HIP_MEMORY_SCOPE_AGENT);
            float m1 = t1 * inv_m;
            float var = fmaxf(t2 * inv_m - m1 * m1, 0.f);
            float inv = rsqrtf(var + BN_EPS);
            float sc = gamma[c] * inv;
            scsh[c] = sc;
            scsh[256 + c] = beta[c] - m1 * sc;
        }
        __syncthreads();

        unsigned short* stash = lds + 8192;
        // two passes: cols [0,128) then [128,256)
#pragma unroll
        for (int h = 0; h < 2; ++h) {
            if (wn == h * 128) {
                // this wave owns these columns: BN+relu+bf16 into stash
#pragma unroll
                for (int mi = 0; mi < 4; ++mi) {
#pragma unroll
                    for (int rg = 0; rg < 4; ++rg) {
                        int rloc = wm + mi * 16 + kq * 4 + rg;
                        int xr = (rloc & 7) << 3;
#pragma unroll
                        for (int ni = 0; ni < 8; ++ni) {
                            int cin = ni * 16 + lm;                 // 0..127 in-half
                            float sc = scsh[h * 128 + cin];
                            float sh = scsh[256 + h * 128 + cin];
                            float r = fmaxf(acc[mi][ni][rg] * sc + sh, 0.f);
                            stash[rloc * 128 + (cin ^ xr)] = f2bf(r);
                        }
                    }
                }
            }
            __syncthreads();
            // coalesced writer: thread t -> row r=t>>1, 64-col run
            {
                const int r = threadIdx.x >> 1;
                const int half = threadIdx.x & 1;
                const int grow = tile_m + r;
                if (grow < M_REAL) {
                    const int xr = (r & 7) << 3;
#pragma unroll
                    for (int ch = 0; ch < 8; ++ch) {
                        int c0 = half * 64 + ch * 8;                // 0..127 in-half
                        short8 sv = *(const short8*)&stash[r * 128 + (c0 ^ xr)];
                        if (LAST) {
                            int gc = h * 128 + c0;
                            f4 w0, w1;
                            w0.x = bf2f((unsigned short)sv[0]);
                            w0.y = bf2f((unsigned short)sv[1]);
                            w0.z = bf2f((unsigned short)sv[2]);
                            w0.w = bf2f((unsigned short)sv[3]);
                            w1.x = bf2f((unsigned short)sv[4]);
                            w1.y = bf2f((unsigned short)sv[5]);
                            w1.z = bf2f((unsigned short)sv[6]);
                            w1.w = bf2f((unsigned short)sv[7]);
                            float* dst = outp + (size_t)grow * 256 + gc;
                            *(f4*)dst = w0;
                            *(f4*)(dst + 4) = w1;
                        } else {
                            *(short8*)(xn + (size_t)grow * 768 + 512 + h * 128 + c0) = sv;
                        }
                    }
                }
            }
            __syncthreads();
        }
    }
}

// ---------------------------------------------------------------------------
// gather in INPUT space: one wave per dst node; 4-edge unroll.
// buf row (stride S=3D(+64)): [u0 0..D | u1 D..2D | x 2D..3D | t-chunk (l0)]
// ---------------------------------------------------------------------------
template<int D, bool HAST>
__global__ __launch_bounds__(256) void gatheru_k(
    unsigned short* buf, const float* __restrict__ comp,
    const unsigned int* __restrict__ rowptr, const float2* __restrict__ erec)
{
    constexpr int E = D / 64;
    constexpr int S = 3 * D + (HAST ? 64 : 0);
    __shared__ float scomp[32];
    if (threadIdx.x < 32) scomp[threadIdx.x] = comp[threadIdx.x];
    __syncthreads();
    int node = blockIdx.x * 4 + (threadIdx.x >> 6);
    int lane = threadIdx.x & 63;
    unsigned int p0 = rowptr[node], p1 = rowptr[node + 1];
    const unsigned short* xbase = buf + 2 * D + lane * E;

    float a0[E], a1[E], b0[E], b1[E];
#pragma unroll
    for (int e = 0; e < E; ++e) { a0[e] = a1[e] = b0[e] = b1[e] = 0.f; }
    float t0 = 0.f, t1 = 0.f;

    unsigned int p = p0;
    for (; p + 4 <= p1; p += 4) {
        float2 r[4];
        unsigned short v[4][E];
#pragma unroll
        for (int j = 0; j < 4; ++j) r[j] = erec[p + j];
#pragma unroll
        for (int j = 0; j < 4; ++j) {
            unsigned q = __float_as_uint(r[j].x);
            const unsigned short* s = xbase + (size_t)(q >> 4) * S;
            if (E == 2) { ushort2 t = *(const ushort2*)s; v[j][0] = t.x; v[j][1] = t.y; }
            else        { ushort4 t = *(const ushort4*)s; v[j][0] = t.x; v[j][1] = t.y;
                          v[j][2] = t.z; v[j][3] = t.w; }
        }
#pragma unroll
        for (int j = 0; j < 4; ++j) {
            unsigned q = __float_as_uint(r[j].x);
            float w0 = scomp[(q & 15) * 2] * r[j].y;
            float w1 = scomp[(q & 15) * 2 + 1] * r[j].y;
            if (HAST) { t0 += w0; t1 += w1; }
            float* d0 = (j & 1) ? b0 : a0;
            float* d1 = (j & 1) ? b1 : a1;
#pragma unroll
            for (int e = 0; e < E; ++e) {
                float xv = bf2f(v[j][e]);
                d0[e] += w0 * xv;
                d1[e] += w1 * xv;
            }
        }
    }
    for (; p < p1; ++p) {
        float2 r = erec[p];
        unsigned q = __float_as_uint(r.x);
        const unsigned short* s = xbase + (size_t)(q >> 4) * S;
        unsigned short v[E];
        if (E == 2) { ushort2 t = *(const ushort2*)s; v[0] = t.x; v[1] = t.y; }
        else        { ushort4 t = *(const ushort4*)s; v[0] = t.x; v[1] = t.y;
                      v[2] = t.z; v[3] = t.w; }
        float w0 = scomp[(q & 15) * 2] * r.y;
        float w1 = scomp[(q & 15) * 2 + 1] * r.y;
        if (HAST) { t0 += w0; t1 += w1; }
#pragma unroll
        for (int e = 0; e < E; ++e) {
            float xv = bf2f(v[e]);
            a0[e] += w0 * xv;
            a1[e] += w1 * xv;
        }
    }

    unsigned short* orow = buf + (size_t)node * S;
    if (E == 2) {
        ushort2 o0, o1;
        o0.x = f2bf(a0[0] + b0[0]); o0.y = f2bf(a0[1] + b0[1]);
        o1.x = f2bf(a1[0] + b1[0]); o1.y = f2bf(a1[1] + b1[1]);
        *(ushort2*)(orow + lane * 2) = o0;
        *(ushort2*)(orow + D + lane * 2) = o1;
    } else {
        ushort4 o0, o1;
        o0.x = f2bf(a0[0] + b0[0]); o0.y = f2bf(a0[1] + b0[1]);
        o0.z = f2bf(a0[2] + b0[2]); o0.w = f2bf(a0[3] + b0[3]);
        o1.x = f2bf(a1[0] + b1[0]); o1.y = f2bf(a1[1] + b1[1]);
        o1.z = f2bf(a1[2] + b1[2]); o1.w = f2bf(a1[3] + b1[3]);
        *(ushort4*)(orow + lane * 4) = o0;
        *(ushort4*)(orow + D + lane * 4) = o1;
    }
    if (HAST) {
        unsigned short tv = (lane == 0) ? f2bf(t0) : (lane == 1) ? f2bf(t1) : (unsigned short)0;
        orow[3 * D + lane] = tv;
    }
}

// row L2-normalize emb -> bf16 x0, into axl0 at col offset 256 (stride 448)
__global__ __launch_bounds__(256) void norm_k(const float* __restrict__ emb,
                                              unsigned short* __restrict__ buf)
{
    int node = blockIdx.x * 4 + (threadIdx.x >> 6);
    int lane = threadIdx.x & 63;
    const float2* p = (const float2*)(emb + (size_t)node * 128);
    float2 v = p[lane];
    float ss = v.x * v.x + v.y * v.y;
#pragma unroll
    for (int o = 32; o > 0; o >>= 1) ss += __shfl_xor(ss, o);
    float inv = 1.f / fmaxf(sqrtf(ss), 1e-12f);
    unsigned short* row = buf + (size_t)node * 448 + 256;
    unsigned int pack = (unsigned int)f2bf(v.x * inv) | ((unsigned int)f2bf(v.y * inv) << 16);
    ((unsigned int*)row)[lane] = pack;
}

// zero cnt(800000) cntd(50000) cursor(50000) bns(1536) bar(3)
__global__ void zero_k(unsigned int* __restrict__ cnt, unsigned int* __restrict__ cntd,
                       unsigned int* __restrict__ cursor, float* __restrict__ bns,
                       unsigned int* __restrict__ bar)
{
    int i = blockIdx.x * 256 + threadIdx.x;
    if (i < 800000) cnt[i] = 0u;
    if (i < 50000) { cntd[i] = 0u; cursor[i] = 0u; }
    if (i < 1536) bns[i] = 0.f;
    if (i < 3) bar[i] = 0u;
}

__global__ void cnt_k(const int* __restrict__ ei, const int* __restrict__ et,
                      unsigned int* __restrict__ cnt, unsigned int* __restrict__ cntd)
{
    int e = blockIdx.x * 256 + threadIdx.x;
    if (e >= NEDGE) return;
    int dst = ei[NEDGE + e];
    atomicAdd(&cnt[(size_t)dst * NREL + et[e]], 1u);
    atomicAdd(&cntd[dst], 1u);
}

__global__ __launch_bounds__(SCAN_B) void scan1_k(const unsigned int* __restrict__ cntd,
                                                  unsigned int* __restrict__ partial,
                                                  unsigned int* __restrict__ bsum)
{
    __shared__ unsigned int s[SCAN_B];
    int i = blockIdx.x * SCAN_B + threadIdx.x;
    unsigned int v = (i < NNODES) ? cntd[i] : 0u;
    s[threadIdx.x] = v;
    __syncthreads();
    for (int off = 1; off < SCAN_B; off <<= 1) {
        unsigned int t = (threadIdx.x >= off) ? s[threadIdx.x - off] : 0u;
        __syncthreads();
        s[threadIdx.x] += t;
        __syncthreads();
    }
    if (i < NNODES) partial[i] = s[threadIdx.x];
    if (threadIdx.x == SCAN_B - 1) bsum[blockIdx.x] = s[SCAN_B - 1];
}

__global__ __launch_bounds__(128) void scan2_k(unsigned int* __restrict__ bsum)
{
    __shared__ unsigned int s[128];
    unsigned int v = (threadIdx.x < SCAN_NB) ? bsum[threadIdx.x] : 0u;
    s[threadIdx.x] = v;
    __syncthreads();
    for (int off = 1; off < 128; off <<= 1) {
        unsigned int t = (threadIdx.x >= off) ? s[threadIdx.x - off] : 0u;
        __syncthreads();
        s[threadIdx.x] += t;
        __syncthreads();
    }
    if (threadIdx.x < SCAN_NB) bsum[threadIdx.x] = s[threadIdx.x];
}

__global__ __launch_bounds__(SCAN_B) void scan3_k(const unsigned int* __restrict__ partial,
                                                  const unsigned int* __restrict__ bsum,
                                                  unsigned int* __restrict__ rowptr)
{
    int i = blockIdx.x * SCAN_B + threadIdx.x;
    if (i >= NNODES) return;
    unsigned int off = (blockIdx.x > 0) ? bsum[blockIdx.x - 1] : 0u;
    rowptr[i + 1] = partial[i] + off;
    if (i == 0) rowptr[0] = 0u;
}

__global__ void fill_k(const int* __restrict__ ei, const int* __restrict__ et,
                       const unsigned int* __restrict__ cnt,
                       const unsigned int* __restrict__ rowptr,
                       unsigned int* __restrict__ cursor,
                       float2* __restrict__ erec)
{
    int e = blockIdx.x * 256 + threadIdx.x;
    if (e >= NEDGE) return;
    int dst = ei[NEDGE + e];
    int t = et[e];
    unsigned int c = cnt[(size_t)dst * NREL + t];
    unsigned int pos = rowptr[dst] + atomicAdd(&cursor[dst], 1u);
    float2 r;
    r.x = __uint_as_float(((unsigned)ei[e] << 4) | (unsigned)t);
    r.y = 1.f / (float)(c ? c : 1u);
    erec[pos] = r;
}

// PT[j*128+d] = proj_w[d*768+j]
__global__ __launch_bounds__(128) void pt_k(const float* __restrict__ proj_w,
                                            float* __restrict__ PT)
{
    int j = blockIdx.x, d = threadIdx.x;
    PT[(size_t)j * 128 + d] = proj_w[(size_t)d * 768 + j];
}

// layer-0 folded weights: wTm0[n][448]: [P@B0 | P@B1 | P@R | pb@B0, pb@B1, 0..]
__global__ __launch_bounds__(128) void pm_k(
    const float* __restrict__ PT, const float* __restrict__ pb,
    const float* __restrict__ b0, const float* __restrict__ r0,
    const float* __restrict__ bias0,
    unsigned short* __restrict__ wTm0, float* __restrict__ biasM0)
{
    __shared__ float sw[128];
    __shared__ float spb[128];
    __shared__ float red[2];
    int seg = blockIdx.x >> 8;
    int n = blockIdx.x & 255;
    int d = threadIdx.x;
    float acc = 0.f, accb = 0.f;
    for (int ch = 0; ch < 6; ++ch) {
        int j0 = ch * 128;
        __syncthreads();
        int j = j0 + d;
        float wv;
        if (seg == 0)      wv = b0[(size_t)j * 256 + n];
        else if (seg == 1) wv = b0[768 * 256 + (size_t)j * 256 + n];
        else               wv = r0[(size_t)j * 256 + n];
        sw[d] = wv;
        spb[d] = pb[j];
        __syncthreads();
#pragma unroll 8
        for (int jj = 0; jj < 128; ++jj)
            acc += PT[(size_t)(j0 + jj) * 128 + d] * sw[jj];
        accb += spb[d] * sw[d];
    }
    for (int o = 32; o > 0; o >>= 1) accb += __shfl_xor(accb, o);
    if ((d & 63) == 0) red[d >> 6] = accb;
    __syncthreads();
    float tb = red[0] + red[1];
    wTm0[(size_t)n * 448 + seg * 128 + d] = f2bf(acc);
    if (seg == 0) { if (d == 0) wTm0[(size_t)n * 448 + 384] = f2bf(tb); }
    else if (seg == 1) { if (d == 0) wTm0[(size_t)n * 448 + 385] = f2bf(tb); }
    else {
        if (d == 0) biasM0[n] = tb + bias0[n];
        if (d >= 2 && d < 64) wTm0[(size_t)n * 448 + 384 + d] = 0;
    }
}

// layers 1/2: wTm[n][768] = [B0 | B1 | R] rows; + biasM fills
__global__ __launch_bounds__(256) void prep_k(
    const float* __restrict__ b1, const float* __restrict__ r1, const float* __restrict__ bias1,
    const float* __restrict__ b2, const float* __restrict__ r2, const float* __restrict__ bias2,
    unsigned short* __restrict__ wTm1, unsigned short* __restrict__ wTm2,
    float* __restrict__ biasM1, float* __restrict__ biasM2)
{
    int b = blockIdx.x;
    int n = threadIdx.x;
    if (b < 1536) {
        int layer = b / 768;
        int rem = b % 768;
        int seg = rem / 256;
        int k = rem % 256;
        const float* bb = layer ? b2 : b1;
        const float* rr = layer ? r2 : r1;
        const float* in = (seg < 2) ? (bb + (size_t)seg * 256 * 256) : rr;
        unsigned short* out = layer ? wTm2 : wTm1;
        out[(size_t)n * 768 + seg * 256 + k] = f2bf(in[(size_t)k * 256 + n]);
    } else {
        int layer = b - 1536;
        float* bm = layer ? biasM2 : biasM1;
        const float* bs = layer ? bias2 : bias1;
        bm[n] = bs[n];
    }
}

extern "C" void kernel_launch(void* const* d_in, const int* in_sizes, int n_in,
                              void* d_out, int out_size, void* d_ws, size_t ws_size,
                              hipStream_t stream)
{
    const int*   edge_index = (const int*)d_in[0];
    const int*   edge_type  = (const int*)d_in[1];
    const float* emb    = (const float*)d_in[2];
    const float* proj_w = (const float*)d_in[3];
    const float* proj_b = (const float*)d_in[4];
    const float* comp[3]  = {(const float*)d_in[5],  (const float*)d_in[11], (const float*)d_in[17]};
    const float* bases[3] = {(const float*)d_in[6],  (const float*)d_in[12], (const float*)d_in[18]};
    const float* root[3]  = {(const float*)d_in[7],  (const float*)d_in[13], (const float*)d_in[19]};
    const float* biasp[3] = {(const float*)d_in[8],  (const float*)d_in[14], (const float*)d_in[20]};
    const float* gamma[3] = {(const float*)d_in[9],  (const float*)d_in[15], (const float*)d_in[21]};
    const float* beta[3]  = {(const float*)d_in[10], (const float*)d_in[16], (const float*)d_in[22]};

    char* ws = (char*)d_ws;
    size_t off = 0;
    auto alloc = [&](size_t bytes) -> char* {
        char* p = ws + off;
        off = (off + bytes + 255) & ~(size_t)255;
        return p;
    };

    unsigned short* axl0 = (unsigned short*)alloc((size_t)NNODES * 448 * 2);
    unsigned short* axl1 = (unsigned short*)alloc((size_t)NNODES * 768 * 2);
    unsigned short* axl2 = (unsigned short*)alloc((size_t)NNODES * 768 * 2);
    unsigned int*   cnt  = (unsigned int*)alloc((size_t)NNODES * NREL * 4);
    unsigned int*   cntd = (unsigned int*)alloc((size_t)NNODES * 4);
    unsigned int*   rowptr = (unsigned int*)alloc((size_t)(NNODES + 1) * 4);
    unsigned int*   cursor = (unsigned int*)alloc((size_t)NNODES * 4);
    unsigned int*   partial = (unsigned int*)alloc((size_t)NNODES * 4);
    unsigned int*   bsum = (unsigned int*)alloc(128 * 4);
    float2*         erec = (float2*)alloc((size_t)NEDGE * 8);
    float*          PT   = (float*)alloc((size_t)768 * 128 * 4);
    unsigned short* wTm0 = (unsigned short*)alloc((size_t)256 * 448 * 2);
    unsigned short* wTm1 = (unsigned short*)alloc((size_t)256 * 768 * 2);
    unsigned short* wTm2 = (unsigned short*)alloc((size_t)256 * 768 * 2);
    float* biasM = (float*)alloc(3 * 256 * 4);
    float* bns   = (float*)alloc(3 * 512 * 4);
    unsigned int* bar = (unsigned int*)alloc(3 * 4);

    zero_k<<<3125, 256, 0, stream>>>(cnt, cntd, cursor, bns, bar);
    norm_k<<<NNODES / 4, 256, 0, stream>>>(emb, axl0);
    cnt_k<<<(NEDGE + 255) / 256, 256, 0, stream>>>(edge_index, edge_type, cnt, cntd);
    scan1_k<<<SCAN_NB, SCAN_B, 0, stream>>>(cntd, partial, bsum);
    scan2_k<<<1, 128, 0, stream>>>(bsum);
    scan3_k<<<SCAN_NB, SCAN_B, 0, stream>>>(partial, bsum, rowptr);
    fill_k<<<(NEDGE + 255) / 256, 256, 0, stream>>>(edge_index, edge_type, cnt, rowptr,
                                                    cursor, erec);

    pt_k<<<768, 128, 0, stream>>>(proj_w, PT);
    pm_k<<<768, 128, 0, stream>>>(PT, proj_b, bases[0], root[0], biasp[0], wTm0, biasM);
    prep_k<<<1538, 256, 0, stream>>>(bases[1], root[1], biasp[1],
                                     bases[2], root[2], biasp[2],
                                     wTm1, wTm2, biasM + 256, biasM + 512);

    // ---- layer 0 (D=128, K=448 with t-chunk) ----
    gatheru_k<128, true><<<NNODES / 4, 256, 0, stream>>>(axl0, comp[0], rowptr, erec);
    gemmf_k<448, false><<<GRIDB, 256, 0, stream>>>(axl0, wTm0, biasM, bns,
                                                   gamma[0], beta[0], axl1, nullptr, bar);

    // ---- layer 1 (D=256, K=768) ----
    gatheru_k<256, false><<<NNODES / 4, 256, 0, stream>>>(axl1, comp[1], rowptr, erec);
    gemmf_k<768, false><<<GRIDB, 256, 0, stream>>>(axl1, wTm1, biasM + 256, bns + 512,
                                                   gamma[1], beta[1], axl2, nullptr, bar + 1);

    // ---- layer 2 (D=256, K=768) ----
    gatheru_k<256, false><<<NNODES / 4, 256, 0, stream>>>(axl2, comp[2], rowptr, erec);
    gemmf_k<768, true><<<GRIDB, 256, 0, stream>>>(axl2, wTm2, biasM + 512, bns + 1024,
                                                  gamma[2], beta[2], nullptr, (float*)d_out, bar + 2);
}

// Round 5
// 517.585 us; speedup vs baseline: 1.9175x; 1.5306x over previous
//
#include <hip/hip_runtime.h>
#include <hip/hip_bf16.h>

#define NNODES 50000
#define NREL   16
#define NEDGE  400000
#define BN_EPS 1e-5f
#define M_REAL NNODES
#define M_TILES 391            /* ceil(50000/128) */
#define RPX    49              /* ceil(391/8) row-blocks per XCD */
#define SCAN_B 512
#define SCAN_NB ((NNODES + SCAN_B - 1) / SCAN_B)   /* 98 */

typedef __attribute__((ext_vector_type(8))) short short8;
typedef __attribute__((ext_vector_type(4))) float f4;

__device__ __forceinline__ float bf2f(unsigned short u) {
    union { unsigned int i; float f; } x; x.i = ((unsigned int)u) << 16; return x.f;
}
__device__ __forceinline__ unsigned short f2bf(float f) {
    __hip_bfloat16 h = __float2bfloat16(f);
    union { __hip_bfloat16 h; unsigned short u; } x; x.h = h; return x.u;
}

__device__ __forceinline__ void g2l16(const unsigned short* g, unsigned short* l) {
    __builtin_amdgcn_global_load_lds(
        (const __attribute__((address_space(1))) unsigned int*)g,
        (__attribute__((address_space(3))) unsigned int*)l,
        16, 0, 0);
}

// ---------------------------------------------------------------------------
// GEMM (R0-verified m97 structure): y[M,256](bf16) = A[M,K] @ WT[256,K]^T
// + bias, + BN sums (s1,s2 per column -> atomics, computed from f32 acc).
// 128x128 tile, BK=64, global_load_lds staging w/ chunk swizzle, XCD swizzle.
// Change vs 528us baseline: y stored as bf16 (halves WRITE_SIZE).
// ---------------------------------------------------------------------------
template<int K>
__global__ __launch_bounds__(256) void gemm3_k(
    const unsigned short* __restrict__ A,
    const unsigned short* __restrict__ WT,
    const float* __restrict__ bias,
    unsigned short* __restrict__ y,
    float* __restrict__ bns)
{
    const int lin = blockIdx.x;
    const int xcd = lin & 7;
    const int idx = lin >> 3;
    const int row_blk = xcd * RPX + (idx >> 1);
    const int nt = idx & 1;
    if (row_blk >= M_TILES) return;
    const int tile_m = row_blk * 128;
    const int tile_n = nt * 128;

    __shared__ unsigned short As[128 * 64];
    __shared__ unsigned short Bs[128 * 64];

    const int w = threadIdx.x >> 6;
    const int l = threadIdx.x & 63;
    const int lm = l & 15;
    const int kq = l >> 4;
    const int wm = (w & 1) << 6;
    const int wn = (w >> 1) << 6;

    const int lrow = l >> 3;
    const int chunk = ((l & 7) + 8 - lrow) & 7;
    const unsigned short* srcA[4];
    const unsigned short* srcB[4];
    unsigned short* dstA[4];
    unsigned short* dstB[4];
#pragma unroll
    for (int it = 0; it < 4; ++it) {
        int rt = it * 32 + w * 8 + lrow;
        int rg = tile_m + rt; if (rg >= M_REAL) rg = M_REAL - 1;
        srcA[it] = A  + (size_t)rg * K + chunk * 8;
        srcB[it] = WT + (size_t)(tile_n + rt) * K + chunk * 8;
        dstA[it] = As + (it * 32 + w * 8) * 64;
        dstB[it] = Bs + (it * 32 + w * 8) * 64;
    }

    unsigned aoff[4], boff[4];
#pragma unroll
    for (int mi = 0; mi < 4; ++mi) {
        aoff[mi] = (unsigned)((wm + mi * 16 + lm) * 128 + (((kq + lm) & 7) << 4));
        boff[mi] = (unsigned)((wn + mi * 16 + lm) * 128 + (((kq + lm) & 7) << 4));
    }

    f4 acc[4][4];
#pragma unroll
    for (int mi = 0; mi < 4; ++mi)
#pragma unroll
        for (int ni = 0; ni < 4; ++ni) acc[mi][ni] = (f4){0.f, 0.f, 0.f, 0.f};

    for (int kc = 0; kc < K; kc += 64) {
#pragma unroll
        for (int it = 0; it < 4; ++it) {
            g2l16(srcA[it] + kc, dstA[it]);
            g2l16(srcB[it] + kc, dstB[it]);
        }
        __syncthreads();
#pragma unroll
        for (int kh = 0; kh < 2; ++kh) {
            const unsigned x = kh << 6;
            short8 af[4], bfr[4];
#pragma unroll
            for (int mi = 0; mi < 4; ++mi)
                af[mi] = *(const short8*)((const char*)As + (aoff[mi] ^ x));
#pragma unroll
            for (int ni = 0; ni < 4; ++ni)
                bfr[ni] = *(const short8*)((const char*)Bs + (boff[ni] ^ x));
#pragma unroll
            for (int mi = 0; mi < 4; ++mi)
#pragma unroll
                for (int ni = 0; ni < 4; ++ni)
                    acc[mi][ni] = __builtin_amdgcn_mfma_f32_16x16x32_bf16(
                        af[mi], bfr[ni], acc[mi][ni], 0, 0, 0);
        }
        __syncthreads();
    }

    int cols[4]; float bv[4];
#pragma unroll
    for (int ni = 0; ni < 4; ++ni) {
        cols[ni] = tile_n + wn + ni * 16 + lm;
        bv[ni] = bias[cols[ni]];
    }
    float s1[4] = {0.f, 0.f, 0.f, 0.f}, s2[4] = {0.f, 0.f, 0.f, 0.f};
#pragma unroll
    for (int mi = 0; mi < 4; ++mi) {
#pragma unroll
        for (int rg = 0; rg < 4; ++rg) {
            int row = tile_m + wm + mi * 16 + kq * 4 + rg;
            if (row < M_REAL) {
                size_t base = (size_t)row * 256;
#pragma unroll
                for (int ni = 0; ni < 4; ++ni) {
                    float v = acc[mi][ni][rg] + bv[ni];
                    y[base + cols[ni]] = f2bf(v);
                    s1[ni] += v; s2[ni] += v * v;
                }
            }
        }
    }
#pragma unroll
    for (int ni = 0; ni < 4; ++ni) {
        float a = s1[ni], b = s2[ni];
        a += __shfl_xor(a, 16); a += __shfl_xor(a, 32);
        b += __shfl_xor(b, 16); b += __shfl_xor(b, 32);
        if (l < 16) {
            atomicAdd(&bns[cols[ni]], a);
            atomicAdd(&bns[256 + cols[ni]], b);
        }
    }
}

// ---------------------------------------------------------------------------
// gather in INPUT space: one wave per dst node; 4-edge unroll.
// buf row (stride S=3D(+64)): [u0 0..D | u1 D..2D | x 2D..3D | t-chunk (l0)]
// ---------------------------------------------------------------------------
template<int D, bool HAST>
__global__ __launch_bounds__(256) void gatheru_k(
    unsigned short* buf, const float* __restrict__ comp,
    const unsigned int* __restrict__ rowptr, const float2* __restrict__ erec)
{
    constexpr int E = D / 64;                 // bf16 elems per lane (2 or 4)
    constexpr int S = 3 * D + (HAST ? 64 : 0);
    __shared__ float scomp[32];
    if (threadIdx.x < 32) scomp[threadIdx.x] = comp[threadIdx.x];
    __syncthreads();
    int node = blockIdx.x * 4 + (threadIdx.x >> 6);
    int lane = threadIdx.x & 63;
    unsigned int p0 = rowptr[node], p1 = rowptr[node + 1];
    const unsigned short* xbase = buf + 2 * D + lane * E;

    float a0[E], a1[E], b0[E], b1[E];
#pragma unroll
    for (int e = 0; e < E; ++e) { a0[e] = a1[e] = b0[e] = b1[e] = 0.f; }
    float t0 = 0.f, t1 = 0.f;

    unsigned int p = p0;
    for (; p + 4 <= p1; p += 4) {
        float2 r[4];
        unsigned short v[4][E];
#pragma unroll
        for (int j = 0; j < 4; ++j) r[j] = erec[p + j];
#pragma unroll
        for (int j = 0; j < 4; ++j) {
            unsigned q = __float_as_uint(r[j].x);
            const unsigned short* s = xbase + (size_t)(q >> 4) * S;
            if (E == 2) { ushort2 t = *(const ushort2*)s; v[j][0] = t.x; v[j][1] = t.y; }
            else        { ushort4 t = *(const ushort4*)s; v[j][0] = t.x; v[j][1] = t.y;
                          v[j][2] = t.z; v[j][3] = t.w; }
        }
#pragma unroll
        for (int j = 0; j < 4; ++j) {
            unsigned q = __float_as_uint(r[j].x);
            float w0 = scomp[(q & 15) * 2] * r[j].y;
            float w1 = scomp[(q & 15) * 2 + 1] * r[j].y;
            if (HAST) { t0 += w0; t1 += w1; }
            float* d0 = (j & 1) ? b0 : a0;
            float* d1 = (j & 1) ? b1 : a1;
#pragma unroll
            for (int e = 0; e < E; ++e) {
                float xv = bf2f(v[j][e]);
                d0[e] += w0 * xv;
                d1[e] += w1 * xv;
            }
        }
    }
    for (; p < p1; ++p) {
        float2 r = erec[p];
        unsigned q = __float_as_uint(r.x);
        const unsigned short* s = xbase + (size_t)(q >> 4) * S;
        unsigned short v[E];
        if (E == 2) { ushort2 t = *(const ushort2*)s; v[0] = t.x; v[1] = t.y; }
        else        { ushort4 t = *(const ushort4*)s; v[0] = t.x; v[1] = t.y;
                      v[2] = t.z; v[3] = t.w; }
        float w0 = scomp[(q & 15) * 2] * r.y;
        float w1 = scomp[(q & 15) * 2 + 1] * r.y;
        if (HAST) { t0 += w0; t1 += w1; }
#pragma unroll
        for (int e = 0; e < E; ++e) {
            float xv = bf2f(v[e]);
            a0[e] += w0 * xv;
            a1[e] += w1 * xv;
        }
    }

    unsigned short* orow = buf + (size_t)node * S;
    if (E == 2) {
        ushort2 o0, o1;
        o0.x = f2bf(a0[0] + b0[0]); o0.y = f2bf(a0[1] + b0[1]);
        o1.x = f2bf(a1[0] + b1[0]); o1.y = f2bf(a1[1] + b1[1]);
        *(ushort2*)(orow + lane * 2) = o0;
        *(ushort2*)(orow + D + lane * 2) = o1;
    } else {
        ushort4 o0, o1;
        o0.x = f2bf(a0[0] + b0[0]); o0.y = f2bf(a0[1] + b0[1]);
        o0.z = f2bf(a0[2] + b0[2]); o0.w = f2bf(a0[3] + b0[3]);
        o1.x = f2bf(a1[0] + b1[0]); o1.y = f2bf(a1[1] + b1[1]);
        o1.z = f2bf(a1[2] + b1[2]); o1.w = f2bf(a1[3] + b1[3]);
        *(ushort4*)(orow + lane * 4) = o0;
        *(ushort4*)(orow + D + lane * 4) = o1;
    }
    if (HAST) {
        unsigned short tv = (lane == 0) ? f2bf(t0) : (lane == 1) ? f2bf(t1) : (unsigned short)0;
        orow[3 * D + lane] = tv;
    }
}

// row L2-normalize emb -> bf16 x0, into axl0 at col offset 256 (stride 448)
__global__ __launch_bounds__(256) void norm_k(const float* __restrict__ emb,
                                              unsigned short* __restrict__ buf)
{
    int node = blockIdx.x * 4 + (threadIdx.x >> 6);
    int lane = threadIdx.x & 63;
    const float2* p = (const float2*)(emb + (size_t)node * 128);
    float2 v = p[lane];
    float ss = v.x * v.x + v.y * v.y;
#pragma unroll
    for (int o = 32; o > 0; o >>= 1) ss += __shfl_xor(ss, o);
    float inv = 1.f / fmaxf(sqrtf(ss), 1e-12f);
    unsigned short* row = buf + (size_t)node * 448 + 256;
    unsigned int pack = (unsigned int)f2bf(v.x * inv) | ((unsigned int)f2bf(v.y * inv) << 16);
    ((unsigned int*)row)[lane] = pack;
}

// zero cnt(800000) cntd(50000) cursor(50000) bns(1536)
__global__ void zero_k(unsigned int* __restrict__ cnt, unsigned int* __restrict__ cntd,
                       unsigned int* __restrict__ cursor, float* __restrict__ bns)
{
    int i = blockIdx.x * 256 + threadIdx.x;
    if (i < 800000) cnt[i] = 0u;
    if (i < 50000) { cntd[i] = 0u; cursor[i] = 0u; }
    if (i < 1536) bns[i] = 0.f;
}

__global__ void cnt_k(const int* __restrict__ ei, const int* __restrict__ et,
                      unsigned int* __restrict__ cnt, unsigned int* __restrict__ cntd)
{
    int e = blockIdx.x * 256 + threadIdx.x;
    if (e >= NEDGE) return;
    int dst = ei[NEDGE + e];
    atomicAdd(&cnt[(size_t)dst * NREL + et[e]], 1u);
    atomicAdd(&cntd[dst], 1u);
}

__global__ __launch_bounds__(SCAN_B) void scan1_k(const unsigned int* __restrict__ cntd,
                                                  unsigned int* __restrict__ partial,
                                                  unsigned int* __restrict__ bsum)
{
    __shared__ unsigned int s[SCAN_B];
    int i = blockIdx.x * SCAN_B + threadIdx.x;
    unsigned int v = (i < NNODES) ? cntd[i] : 0u;
    s[threadIdx.x] = v;
    __syncthreads();
    for (int off = 1; off < SCAN_B; off <<= 1) {
        unsigned int t = (threadIdx.x >= off) ? s[threadIdx.x - off] : 0u;
        __syncthreads();
        s[threadIdx.x] += t;
        __syncthreads();
    }
    if (i < NNODES) partial[i] = s[threadIdx.x];
    if (threadIdx.x == SCAN_B - 1) bsum[blockIdx.x] = s[SCAN_B - 1];
}

__global__ __launch_bounds__(128) void scan2_k(unsigned int* __restrict__ bsum)
{
    __shared__ unsigned int s[128];
    unsigned int v = (threadIdx.x < SCAN_NB) ? bsum[threadIdx.x] : 0u;
    s[threadIdx.x] = v;
    __syncthreads();
    for (int off = 1; off < 128; off <<= 1) {
        unsigned int t = (threadIdx.x >= off) ? s[threadIdx.x - off] : 0u;
        __syncthreads();
        s[threadIdx.x] += t;
        __syncthreads();
    }
    if (threadIdx.x < SCAN_NB) bsum[threadIdx.x] = s[threadIdx.x];
}

__global__ __launch_bounds__(SCAN_B) void scan3_k(const unsigned int* __restrict__ partial,
                                                  const unsigned int* __restrict__ bsum,
                                                  unsigned int* __restrict__ rowptr)
{
    int i = blockIdx.x * SCAN_B + threadIdx.x;
    if (i >= NNODES) return;
    unsigned int off = (blockIdx.x > 0) ? bsum[blockIdx.x - 1] : 0u;
    rowptr[i + 1] = partial[i] + off;
    if (i == 0) rowptr[0] = 0u;
}

__global__ void fill_k(const int* __restrict__ ei, const int* __restrict__ et,
                       const unsigned int* __restrict__ cnt,
                       const unsigned int* __restrict__ rowptr,
                       unsigned int* __restrict__ cursor,
                       float2* __restrict__ erec)
{
    int e = blockIdx.x * 256 + threadIdx.x;
    if (e >= NEDGE) return;
    int dst = ei[NEDGE + e];
    int t = et[e];
    unsigned int c = cnt[(size_t)dst * NREL + t];
    unsigned int pos = rowptr[dst] + atomicAdd(&cursor[dst], 1u);
    float2 r;
    r.x = __uint_as_float(((unsigned)ei[e] << 4) | (unsigned)t);
    r.y = 1.f / (float)(c ? c : 1u);
    erec[pos] = r;
}

// PT[j*128+d] = proj_w[d*768+j]
__global__ __launch_bounds__(128) void pt_k(const float* __restrict__ proj_w,
                                            float* __restrict__ PT)
{
    int j = blockIdx.x, d = threadIdx.x;
    PT[(size_t)j * 128 + d] = proj_w[(size_t)d * 768 + j];
}

// layer-0 folded weights: wTm0[n][448]: [P@B0 | P@B1 | P@R | pb@B0, pb@B1, 0..]
__global__ __launch_bounds__(128) void pm_k(
    const float* __restrict__ PT, const float* __restrict__ pb,
    const float* __restrict__ b0, const float* __restrict__ r0,
    const float* __restrict__ bias0,
    unsigned short* __restrict__ wTm0, float* __restrict__ biasM0)
{
    __shared__ float sw[128];
    __shared__ float spb[128];
    __shared__ float red[2];
    int seg = blockIdx.x >> 8;
    int n = blockIdx.x & 255;
    int d = threadIdx.x;
    float acc = 0.f, accb = 0.f;
    for (int ch = 0; ch < 6; ++ch) {
        int j0 = ch * 128;
        __syncthreads();
        int j = j0 + d;
        float wv;
        if (seg == 0)      wv = b0[(size_t)j * 256 + n];
        else if (seg == 1) wv = b0[768 * 256 + (size_t)j * 256 + n];
        else               wv = r0[(size_t)j * 256 + n];
        sw[d] = wv;
        spb[d] = pb[j];
        __syncthreads();
#pragma unroll 8
        for (int jj = 0; jj < 128; ++jj)
            acc += PT[(size_t)(j0 + jj) * 128 + d] * sw[jj];
        accb += spb[d] * sw[d];
    }
    for (int o = 32; o > 0; o >>= 1) accb += __shfl_xor(accb, o);
    if ((d & 63) == 0) red[d >> 6] = accb;
    __syncthreads();
    float tb = red[0] + red[1];
    wTm0[(size_t)n * 448 + seg * 128 + d] = f2bf(acc);
    if (seg == 0) { if (d == 0) wTm0[(size_t)n * 448 + 384] = f2bf(tb); }
    else if (seg == 1) { if (d == 0) wTm0[(size_t)n * 448 + 385] = f2bf(tb); }
    else {
        if (d == 0) biasM0[n] = tb + bias0[n];
        if (d >= 2 && d < 64) wTm0[(size_t)n * 448 + 384 + d] = 0;
    }
}

// layers 1/2: wTm[n][768] = [B0 | B1 | R] rows; + biasM fills
__global__ __launch_bounds__(256) void prep_k(
    const float* __restrict__ b1, const float* __restrict__ r1, const float* __restrict__ bias1,
    const float* __restrict__ b2, const float* __restrict__ r2, const float* __restrict__ bias2,
    unsigned short* __restrict__ wTm1, unsigned short* __restrict__ wTm2,
    float* __restrict__ biasM1, float* __restrict__ biasM2)
{
    int b = blockIdx.x;
    int n = threadIdx.x;
    if (b < 1536) {
        int layer = b / 768;
        int rem = b % 768;
        int seg = rem / 256;
        int k = rem % 256;
        const float* bb = layer ? b2 : b1;
        const float* rr = layer ? r2 : r1;
        const float* in = (seg < 2) ? (bb + (size_t)seg * 256 * 256) : rr;
        unsigned short* out = layer ? wTm2 : wTm1;
        out[(size_t)n * 768 + seg * 256 + k] = f2bf(in[(size_t)k * 256 + n]);
    } else {
        int layer = b - 1536;
        float* bm = layer ? biasM2 : biasM1;
        const float* bs = layer ? bias2 : bias1;
        bm[n] = bs[n];
    }
}

// bf16 y -> BN(scale/shift from bns, computed in-block) + relu -> bf16 x into
// next layer's buf (stride 768, offset 512), or f32 d_out. 8 cols/thread.
template<bool LAST>
__global__ __launch_bounds__(256) void apply_k(const unsigned short* __restrict__ y,
                                               const float* __restrict__ bns,
                                               const float* __restrict__ gamma,
                                               const float* __restrict__ beta,
                                               unsigned short* __restrict__ xn,
                                               float* __restrict__ outp)
{
    __shared__ float scsh[512];
    {
        const float inv_m = 1.f / (float)M_REAL;
        int c = threadIdx.x;
        float m1 = bns[c] * inv_m;
        float var = fmaxf(bns[256 + c] * inv_m - m1 * m1, 0.f);
        float inv = rsqrtf(var + BN_EPS);
        float sc = gamma[c] * inv;
        scsh[c] = sc;
        scsh[256 + c] = beta[c] - m1 * sc;
    }
    __syncthreads();

    int i = blockIdx.x * 256 + threadIdx.x;
    int row = i >> 5;
    int c8 = (i & 31) * 8;
    short8 v = *(const short8*)(y + (size_t)row * 256 + c8);
    f4 sca = *(const f4*)&scsh[c8];
    f4 scb = *(const f4*)&scsh[c8 + 4];
    f4 sha = *(const f4*)&scsh[256 + c8];
    f4 shb = *(const f4*)&scsh[256 + c8 + 4];
    float o0 = fmaxf(bf2f((unsigned short)v[0]) * sca.x + sha.x, 0.f);
    float o1 = fmaxf(bf2f((unsigned short)v[1]) * sca.y + sha.y, 0.f);
    float o2 = fmaxf(bf2f((unsigned short)v[2]) * sca.z + sha.z, 0.f);
    float o3 = fmaxf(bf2f((unsigned short)v[3]) * sca.w + sha.w, 0.f);
    float o4 = fmaxf(bf2f((unsigned short)v[4]) * scb.x + shb.x, 0.f);
    float o5 = fmaxf(bf2f((unsigned short)v[5]) * scb.y + shb.y, 0.f);
    float o6 = fmaxf(bf2f((unsigned short)v[6]) * scb.z + shb.z, 0.f);
    float o7 = fmaxf(bf2f((unsigned short)v[7]) * scb.w + shb.w, 0.f);
    if (LAST) {
        f4 w0 = {o0, o1, o2, o3};
        f4 w1 = {o4, o5, o6, o7};
        float* dst = outp + (size_t)row * 256 + c8;
        *(f4*)dst = w0;
        *(f4*)(dst + 4) = w1;
    } else {
        short8 u;
        u[0] = (short)f2bf(o0); u[1] = (short)f2bf(o1);
        u[2] = (short)f2bf(o2); u[3] = (short)f2bf(o3);
        u[4] = (short)f2bf(o4); u[5] = (short)f2bf(o5);
        u[6] = (short)f2bf(o6); u[7] = (short)f2bf(o7);
        *(short8*)(xn + (size_t)row * 768 + 512 + c8) = u;
    }
}

extern "C" void kernel_launch(void* const* d_in, const int* in_sizes, int n_in,
                              void* d_out, int out_size, void* d_ws, size_t ws_size,
                              hipStream_t stream)
{
    const int*   edge_index = (const int*)d_in[0];
    const int*   edge_type  = (const int*)d_in[1];
    const float* emb    = (const float*)d_in[2];
    const float* proj_w = (const float*)d_in[3];
    const float* proj_b = (const float*)d_in[4];
    const float* comp[3]  = {(const float*)d_in[5],  (const float*)d_in[11], (const float*)d_in[17]};
    const float* bases[3] = {(const float*)d_in[6],  (const float*)d_in[12], (const float*)d_in[18]};
    const float* root[3]  = {(const float*)d_in[7],  (const float*)d_in[13], (const float*)d_in[19]};
    const float* biasp[3] = {(const float*)d_in[8],  (const float*)d_in[14], (const float*)d_in[20]};
    const float* gamma[3] = {(const float*)d_in[9],  (const float*)d_in[15], (const float*)d_in[21]};
    const float* beta[3]  = {(const float*)d_in[10], (const float*)d_in[16], (const float*)d_in[22]};

    char* ws = (char*)d_ws;
    size_t off = 0;
    auto alloc = [&](size_t bytes) -> char* {
        char* p = ws + off;
        off = (off + bytes + 255) & ~(size_t)255;
        return p;
    };

    unsigned short* axl0 = (unsigned short*)alloc((size_t)NNODES * 448 * 2);
    unsigned short* axl1 = (unsigned short*)alloc((size_t)NNODES * 768 * 2);
    unsigned short* axl2 = (unsigned short*)alloc((size_t)NNODES * 768 * 2);
    unsigned short* y    = (unsigned short*)alloc((size_t)NNODES * 256 * 2);
    unsigned int*   cnt  = (unsigned int*)alloc((size_t)NNODES * NREL * 4);
    unsigned int*   cntd = (unsigned int*)alloc((size_t)NNODES * 4);
    unsigned int*   rowptr = (unsigned int*)alloc((size_t)(NNODES + 1) * 4);
    unsigned int*   cursor = (unsigned int*)alloc((size_t)NNODES * 4);
    unsigned int*   partial = (unsigned int*)alloc((size_t)NNODES * 4);
    unsigned int*   bsum = (unsigned int*)alloc(128 * 4);
    float2*         erec = (float2*)alloc((size_t)NEDGE * 8);
    float*          PT   = (float*)alloc((size_t)768 * 128 * 4);
    unsigned short* wTm0 = (unsigned short*)alloc((size_t)256 * 448 * 2);
    unsigned short* wTm1 = (unsigned short*)alloc((size_t)256 * 768 * 2);
    unsigned short* wTm2 = (unsigned short*)alloc((size_t)256 * 768 * 2);
    float* biasM = (float*)alloc(3 * 256 * 4);
    float* bns   = (float*)alloc(3 * 512 * 4);

    zero_k<<<3125, 256, 0, stream>>>(cnt, cntd, cursor, bns);
    norm_k<<<NNODES / 4, 256, 0, stream>>>(emb, axl0);
    cnt_k<<<(NEDGE + 255) / 256, 256, 0, stream>>>(edge_index, edge_type, cnt, cntd);
    scan1_k<<<SCAN_NB, SCAN_B, 0, stream>>>(cntd, partial, bsum);
    scan2_k<<<1, 128, 0, stream>>>(bsum);
    scan3_k<<<SCAN_NB, SCAN_B, 0, stream>>>(partial, bsum, rowptr);
    fill_k<<<(NEDGE + 255) / 256, 256, 0, stream>>>(edge_index, edge_type, cnt, rowptr,
                                                    cursor, erec);

    pt_k<<<768, 128, 0, stream>>>(proj_w, PT);
    pm_k<<<768, 128, 0, stream>>>(PT, proj_b, bases[0], root[0], biasp[0], wTm0, biasM);
    prep_k<<<1538, 256, 0, stream>>>(bases[1], root[1], biasp[1],
                                     bases[2], root[2], biasp[2],
                                     wTm1, wTm2, biasM + 256, biasM + 512);

    // ---- layer 0 (D=128, K=448 with t-chunk) ----
    gatheru_k<128, true><<<NNODES / 4, 256, 0, stream>>>(axl0, comp[0], rowptr, erec);
    gemm3_k<448><<<8 * RPX * 2, 256, 0, stream>>>(axl0, wTm0, biasM, y, bns);
    apply_k<false><<<(NNODES * 32) / 256, 256, 0, stream>>>(y, bns, gamma[0], beta[0],
                                                            axl1, nullptr);

    // ---- layer 1 (D=256, K=768) ----
    gatheru_k<256, false><<<NNODES / 4, 256, 0, stream>>>(axl1, comp[1], rowptr, erec);
    gemm3_k<768><<<8 * RPX * 2, 256, 0, stream>>>(axl1, wTm1, biasM + 256, y, bns + 512);
    apply_k<false><<<(NNODES * 32) / 256, 256, 0, stream>>>(y, bns + 512, gamma[1], beta[1],
                                                            axl2, nullptr);

    // ---- layer 2 (D=256, K=768) ----
    gatheru_k<256, false><<<NNODES / 4, 256, 0, stream>>>(axl2, comp[2], rowptr, erec);
    gemm3_k<768><<<8 * RPX * 2, 256, 0, stream>>>(axl2, wTm2, biasM + 512, y, bns + 1024);
    apply_k<true><<<(NNODES * 32) / 256, 256, 0, stream>>>(y, bns + 1024, gamma[2], beta[2],
                                                           nullptr, (float*)d_out);
}

// Round 6
// 517.260 us; speedup vs baseline: 1.9187x; 1.0006x over previous
//
#include <hip/hip_runtime.h>
#include <hip/hip_bf16.h>

#define NNODES 50000
#define NREL   16
#define NEDGE  400000
#define BN_EPS 1e-5f
#define M_REAL NNODES
#define M_TILES 391            /* ceil(50000/128) */
#define RPX    49              /* ceil(391/8) row-blocks per XCD */
#define SCAN_B 512
#define SCAN_NB ((NNODES + SCAN_B - 1) / SCAN_B)   /* 98 */

typedef __attribute__((ext_vector_type(8))) short short8;
typedef __attribute__((ext_vector_type(4))) float f4;

__device__ __forceinline__ float bf2f(unsigned short u) {
    union { unsigned int i; float f; } x; x.i = ((unsigned int)u) << 16; return x.f;
}
__device__ __forceinline__ unsigned short f2bf(float f) {
    __hip_bfloat16 h = __float2bfloat16(f);
    union { __hip_bfloat16 h; unsigned short u; } x; x.h = h; return x.u;
}

__device__ __forceinline__ void g2l16(const unsigned short* g, unsigned short* l) {
    __builtin_amdgcn_global_load_lds(
        (const __attribute__((address_space(1))) unsigned int*)g,
        (__attribute__((address_space(3))) unsigned int*)l,
        16, 0, 0);
}

// ---------------------------------------------------------------------------
// GEMM: y[M,256](bf16) = A[M,K] @ WT[256,K]^T + bias, + BN sums (atomics).
// 128x128 tile, BK=64, XCD swizzle. R6 change: DOUBLE-BUFFERED staging
// (guide T3 minimum-2-phase): issue next tile's global_load_lds BEFORE the
// ds_read+MFMA of the current tile; one __syncthreads per step drains both.
// Hides the ~900cyc HBM latency that the single-buffer version exposed
// every K-step (gemm was 5x above both HBM and MFMA rooflines).
// LDS 64KB -> 2 blocks/CU.
// ---------------------------------------------------------------------------
template<int K>
__global__ __launch_bounds__(256) void gemm3_k(
    const unsigned short* __restrict__ A,
    const unsigned short* __restrict__ WT,
    const float* __restrict__ bias,
    unsigned short* __restrict__ y,
    float* __restrict__ bns)
{
    const int lin = blockIdx.x;
    const int xcd = lin & 7;
    const int idx = lin >> 3;
    const int row_blk = xcd * RPX + (idx >> 1);
    const int nt = idx & 1;
    if (row_blk >= M_TILES) return;
    const int tile_m = row_blk * 128;
    const int tile_n = nt * 128;

    __shared__ unsigned short As[2][128 * 64];
    __shared__ unsigned short Bs[2][128 * 64];

    const int w = threadIdx.x >> 6;
    const int l = threadIdx.x & 63;
    const int lm = l & 15;
    const int kq = l >> 4;
    const int wm = (w & 1) << 6;
    const int wn = (w >> 1) << 6;

    const int lrow = l >> 3;
    const int chunk = ((l & 7) + 8 - lrow) & 7;
    const unsigned short* srcA[4];
    const unsigned short* srcB[4];
    int dstoff[4];
#pragma unroll
    for (int it = 0; it < 4; ++it) {
        int rt = it * 32 + w * 8 + lrow;
        int rg = tile_m + rt; if (rg >= M_REAL) rg = M_REAL - 1;
        srcA[it] = A  + (size_t)rg * K + chunk * 8;
        srcB[it] = WT + (size_t)(tile_n + rt) * K + chunk * 8;
        dstoff[it] = (it * 32 + w * 8) * 64;
    }

    unsigned aoff[4], boff[4];
#pragma unroll
    for (int mi = 0; mi < 4; ++mi) {
        aoff[mi] = (unsigned)((wm + mi * 16 + lm) * 128 + (((kq + lm) & 7) << 4));
        boff[mi] = (unsigned)((wn + mi * 16 + lm) * 128 + (((kq + lm) & 7) << 4));
    }

    f4 acc[4][4];
#pragma unroll
    for (int mi = 0; mi < 4; ++mi)
#pragma unroll
        for (int ni = 0; ni < 4; ++ni) acc[mi][ni] = (f4){0.f, 0.f, 0.f, 0.f};

    // prologue: stage tile 0 into buffer 0
#pragma unroll
    for (int it = 0; it < 4; ++it) {
        g2l16(srcA[it], As[0] + dstoff[it]);
        g2l16(srcB[it], Bs[0] + dstoff[it]);
    }
    __syncthreads();

    int cur = 0;
    for (int kc = 0; kc < K; kc += 64) {
        // issue next tile's loads FIRST (overlap with compute below)
        if (kc + 64 < K) {
#pragma unroll
            for (int it = 0; it < 4; ++it) {
                g2l16(srcA[it] + kc + 64, As[cur ^ 1] + dstoff[it]);
                g2l16(srcB[it] + kc + 64, Bs[cur ^ 1] + dstoff[it]);
            }
        }
        // compute current buffer
#pragma unroll
        for (int kh = 0; kh < 2; ++kh) {
            const unsigned x = kh << 6;
            short8 af[4], bfr[4];
#pragma unroll
            for (int mi = 0; mi < 4; ++mi)
                af[mi] = *(const short8*)((const char*)As[cur] + (aoff[mi] ^ x));
#pragma unroll
            for (int ni = 0; ni < 4; ++ni)
                bfr[ni] = *(const short8*)((const char*)Bs[cur] + (boff[ni] ^ x));
#pragma unroll
            for (int mi = 0; mi < 4; ++mi)
#pragma unroll
                for (int ni = 0; ni < 4; ++ni)
                    acc[mi][ni] = __builtin_amdgcn_mfma_f32_16x16x32_bf16(
                        af[mi], bfr[ni], acc[mi][ni], 0, 0, 0);
        }
        __syncthreads();   // drains prefetch (vmcnt) + LDS reads; next buf ready
        cur ^= 1;
    }

    int cols[4]; float bv[4];
#pragma unroll
    for (int ni = 0; ni < 4; ++ni) {
        cols[ni] = tile_n + wn + ni * 16 + lm;
        bv[ni] = bias[cols[ni]];
    }
    float s1[4] = {0.f, 0.f, 0.f, 0.f}, s2[4] = {0.f, 0.f, 0.f, 0.f};
#pragma unroll
    for (int mi = 0; mi < 4; ++mi) {
#pragma unroll
        for (int rg = 0; rg < 4; ++rg) {
            int row = tile_m + wm + mi * 16 + kq * 4 + rg;
            if (row < M_REAL) {
                size_t base = (size_t)row * 256;
#pragma unroll
                for (int ni = 0; ni < 4; ++ni) {
                    float v = acc[mi][ni][rg] + bv[ni];
                    y[base + cols[ni]] = f2bf(v);
                    s1[ni] += v; s2[ni] += v * v;
                }
            }
        }
    }
#pragma unroll
    for (int ni = 0; ni < 4; ++ni) {
        float a = s1[ni], b = s2[ni];
        a += __shfl_xor(a, 16); a += __shfl_xor(a, 32);
        b += __shfl_xor(b, 16); b += __shfl_xor(b, 32);
        if (l < 16) {
            atomicAdd(&bns[cols[ni]], a);
            atomicAdd(&bns[256 + cols[ni]], b);
        }
    }
}

// ---------------------------------------------------------------------------
// gather in INPUT space: one wave per dst node; 4-edge unroll.
// buf row (stride S=3D(+64)): [u0 0..D | u1 D..2D | x 2D..3D | t-chunk (l0)]
// ---------------------------------------------------------------------------
template<int D, bool HAST>
__global__ __launch_bounds__(256) void gatheru_k(
    unsigned short* buf, const float* __restrict__ comp,
    const unsigned int* __restrict__ rowptr, const float2* __restrict__ erec)
{
    constexpr int E = D / 64;                 // bf16 elems per lane (2 or 4)
    constexpr int S = 3 * D + (HAST ? 64 : 0);
    __shared__ float scomp[32];
    if (threadIdx.x < 32) scomp[threadIdx.x] = comp[threadIdx.x];
    __syncthreads();
    int node = blockIdx.x * 4 + (threadIdx.x >> 6);
    int lane = threadIdx.x & 63;
    unsigned int p0 = rowptr[node], p1 = rowptr[node + 1];
    const unsigned short* xbase = buf + 2 * D + lane * E;

    float a0[E], a1[E], b0[E], b1[E];
#pragma unroll
    for (int e = 0; e < E; ++e) { a0[e] = a1[e] = b0[e] = b1[e] = 0.f; }
    float t0 = 0.f, t1 = 0.f;

    unsigned int p = p0;
    for (; p + 4 <= p1; p += 4) {
        float2 r[4];
        unsigned short v[4][E];
#pragma unroll
        for (int j = 0; j < 4; ++j) r[j] = erec[p + j];
#pragma unroll
        for (int j = 0; j < 4; ++j) {
            unsigned q = __float_as_uint(r[j].x);
            const unsigned short* s = xbase + (size_t)(q >> 4) * S;
            if (E == 2) { ushort2 t = *(const ushort2*)s; v[j][0] = t.x; v[j][1] = t.y; }
            else        { ushort4 t = *(const ushort4*)s; v[j][0] = t.x; v[j][1] = t.y;
                          v[j][2] = t.z; v[j][3] = t.w; }
        }
#pragma unroll
        for (int j = 0; j < 4; ++j) {
            unsigned q = __float_as_uint(r[j].x);
            float w0 = scomp[(q & 15) * 2] * r[j].y;
            float w1 = scomp[(q & 15) * 2 + 1] * r[j].y;
            if (HAST) { t0 += w0; t1 += w1; }
            float* d0 = (j & 1) ? b0 : a0;
            float* d1 = (j & 1) ? b1 : a1;
#pragma unroll
            for (int e = 0; e < E; ++e) {
                float xv = bf2f(v[j][e]);
                d0[e] += w0 * xv;
                d1[e] += w1 * xv;
            }
        }
    }
    for (; p < p1; ++p) {
        float2 r = erec[p];
        unsigned q = __float_as_uint(r.x);
        const unsigned short* s = xbase + (size_t)(q >> 4) * S;
        unsigned short v[E];
        if (E == 2) { ushort2 t = *(const ushort2*)s; v[0] = t.x; v[1] = t.y; }
        else        { ushort4 t = *(const ushort4*)s; v[0] = t.x; v[1] = t.y;
                      v[2] = t.z; v[3] = t.w; }
        float w0 = scomp[(q & 15) * 2] * r.y;
        float w1 = scomp[(q & 15) * 2 + 1] * r.y;
        if (HAST) { t0 += w0; t1 += w1; }
#pragma unroll
        for (int e = 0; e < E; ++e) {
            float xv = bf2f(v[e]);
            a0[e] += w0 * xv;
            a1[e] += w1 * xv;
        }
    }

    unsigned short* orow = buf + (size_t)node * S;
    if (E == 2) {
        ushort2 o0, o1;
        o0.x = f2bf(a0[0] + b0[0]); o0.y = f2bf(a0[1] + b0[1]);
        o1.x = f2bf(a1[0] + b1[0]); o1.y = f2bf(a1[1] + b1[1]);
        *(ushort2*)(orow + lane * 2) = o0;
        *(ushort2*)(orow + D + lane * 2) = o1;
    } else {
        ushort4 o0, o1;
        o0.x = f2bf(a0[0] + b0[0]); o0.y = f2bf(a0[1] + b0[1]);
        o0.z = f2bf(a0[2] + b0[2]); o0.w = f2bf(a0[3] + b0[3]);
        o1.x = f2bf(a1[0] + b1[0]); o1.y = f2bf(a1[1] + b1[1]);
        o1.z = f2bf(a1[2] + b1[2]); o1.w = f2bf(a1[3] + b1[3]);
        *(ushort4*)(orow + lane * 4) = o0;
        *(ushort4*)(orow + D + lane * 4) = o1;
    }
    if (HAST) {
        unsigned short tv = (lane == 0) ? f2bf(t0) : (lane == 1) ? f2bf(t1) : (unsigned short)0;
        orow[3 * D + lane] = tv;
    }
}

// row L2-normalize emb -> bf16 x0, into axl0 at col offset 256 (stride 448)
__global__ __launch_bounds__(256) void norm_k(const float* __restrict__ emb,
                                              unsigned short* __restrict__ buf)
{
    int node = blockIdx.x * 4 + (threadIdx.x >> 6);
    int lane = threadIdx.x & 63;
    const float2* p = (const float2*)(emb + (size_t)node * 128);
    float2 v = p[lane];
    float ss = v.x * v.x + v.y * v.y;
#pragma unroll
    for (int o = 32; o > 0; o >>= 1) ss += __shfl_xor(ss, o);
    float inv = 1.f / fmaxf(sqrtf(ss), 1e-12f);
    unsigned short* row = buf + (size_t)node * 448 + 256;
    unsigned int pack = (unsigned int)f2bf(v.x * inv) | ((unsigned int)f2bf(v.y * inv) << 16);
    ((unsigned int*)row)[lane] = pack;
}

// zero cnt(800000) cntd(50000) cursor(50000) bns(1536)
__global__ void zero_k(unsigned int* __restrict__ cnt, unsigned int* __restrict__ cntd,
                       unsigned int* __restrict__ cursor, float* __restrict__ bns)
{
    int i = blockIdx.x * 256 + threadIdx.x;
    if (i < 800000) cnt[i] = 0u;
    if (i < 50000) { cntd[i] = 0u; cursor[i] = 0u; }
    if (i < 1536) bns[i] = 0.f;
}

__global__ void cnt_k(const int* __restrict__ ei, const int* __restrict__ et,
                      unsigned int* __restrict__ cnt, unsigned int* __restrict__ cntd)
{
    int e = blockIdx.x * 256 + threadIdx.x;
    if (e >= NEDGE) return;
    int dst = ei[NEDGE + e];
    atomicAdd(&cnt[(size_t)dst * NREL + et[e]], 1u);
    atomicAdd(&cntd[dst], 1u);
}

__global__ __launch_bounds__(SCAN_B) void scan1_k(const unsigned int* __restrict__ cntd,
                                                  unsigned int* __restrict__ partial,
                                                  unsigned int* __restrict__ bsum)
{
    __shared__ unsigned int s[SCAN_B];
    int i = blockIdx.x * SCAN_B + threadIdx.x;
    unsigned int v = (i < NNODES) ? cntd[i] : 0u;
    s[threadIdx.x] = v;
    __syncthreads();
    for (int off = 1; off < SCAN_B; off <<= 1) {
        unsigned int t = (threadIdx.x >= off) ? s[threadIdx.x - off] : 0u;
        __syncthreads();
        s[threadIdx.x] += t;
        __syncthreads();
    }
    if (i < NNODES) partial[i] = s[threadIdx.x];
    if (threadIdx.x == SCAN_B - 1) bsum[blockIdx.x] = s[SCAN_B - 1];
}

__global__ __launch_bounds__(128) void scan2_k(unsigned int* __restrict__ bsum)
{
    __shared__ unsigned int s[128];
    unsigned int v = (threadIdx.x < SCAN_NB) ? bsum[threadIdx.x] : 0u;
    s[threadIdx.x] = v;
    __syncthreads();
    for (int off = 1; off < 128; off <<= 1) {
        unsigned int t = (threadIdx.x >= off) ? s[threadIdx.x - off] : 0u;
        __syncthreads();
        s[threadIdx.x] += t;
        __syncthreads();
    }
    if (threadIdx.x < SCAN_NB) bsum[threadIdx.x] = s[threadIdx.x];
}

__global__ __launch_bounds__(SCAN_B) void scan3_k(const unsigned int* __restrict__ partial,
                                                  const unsigned int* __restrict__ bsum,
                                                  unsigned int* __restrict__ rowptr)
{
    int i = blockIdx.x * SCAN_B + threadIdx.x;
    if (i >= NNODES) return;
    unsigned int off = (blockIdx.x > 0) ? bsum[blockIdx.x - 1] : 0u;
    rowptr[i + 1] = partial[i] + off;
    if (i == 0) rowptr[0] = 0u;
}

__global__ void fill_k(const int* __restrict__ ei, const int* __restrict__ et,
                       const unsigned int* __restrict__ cnt,
                       const unsigned int* __restrict__ rowptr,
                       unsigned int* __restrict__ cursor,
                       float2* __restrict__ erec)
{
    int e = blockIdx.x * 256 + threadIdx.x;
    if (e >= NEDGE) return;
    int dst = ei[NEDGE + e];
    int t = et[e];
    unsigned int c = cnt[(size_t)dst * NREL + t];
    unsigned int pos = rowptr[dst] + atomicAdd(&cursor[dst], 1u);
    float2 r;
    r.x = __uint_as_float(((unsigned)ei[e] << 4) | (unsigned)t);
    r.y = 1.f / (float)(c ? c : 1u);
    erec[pos] = r;
}

// PT[j*128+d] = proj_w[d*768+j]
__global__ __launch_bounds__(128) void pt_k(const float* __restrict__ proj_w,
                                            float* __restrict__ PT)
{
    int j = blockIdx.x, d = threadIdx.x;
    PT[(size_t)j * 128 + d] = proj_w[(size_t)d * 768 + j];
}

// layer-0 folded weights: wTm0[n][448]: [P@B0 | P@B1 | P@R | pb@B0, pb@B1, 0..]
__global__ __launch_bounds__(128) void pm_k(
    const float* __restrict__ PT, const float* __restrict__ pb,
    const float* __restrict__ b0, const float* __restrict__ r0,
    const float* __restrict__ bias0,
    unsigned short* __restrict__ wTm0, float* __restrict__ biasM0)
{
    __shared__ float sw[128];
    __shared__ float spb[128];
    __shared__ float red[2];
    int seg = blockIdx.x >> 8;
    int n = blockIdx.x & 255;
    int d = threadIdx.x;
    float acc = 0.f, accb = 0.f;
    for (int ch = 0; ch < 6; ++ch) {
        int j0 = ch * 128;
        __syncthreads();
        int j = j0 + d;
        float wv;
        if (seg == 0)      wv = b0[(size_t)j * 256 + n];
        else if (seg == 1) wv = b0[768 * 256 + (size_t)j * 256 + n];
        else               wv = r0[(size_t)j * 256 + n];
        sw[d] = wv;
        spb[d] = pb[j];
        __syncthreads();
#pragma unroll 8
        for (int jj = 0; jj < 128; ++jj)
            acc += PT[(size_t)(j0 + jj) * 128 + d] * sw[jj];
        accb += spb[d] * sw[d];
    }
    for (int o = 32; o > 0; o >>= 1) accb += __shfl_xor(accb, o);
    if ((d & 63) == 0) red[d >> 6] = accb;
    __syncthreads();
    float tb = red[0] + red[1];
    wTm0[(size_t)n * 448 + seg * 128 + d] = f2bf(acc);
    if (seg == 0) { if (d == 0) wTm0[(size_t)n * 448 + 384] = f2bf(tb); }
    else if (seg == 1) { if (d == 0) wTm0[(size_t)n * 448 + 385] = f2bf(tb); }
    else {
        if (d == 0) biasM0[n] = tb + bias0[n];
        if (d >= 2 && d < 64) wTm0[(size_t)n * 448 + 384 + d] = 0;
    }
}

// layers 1/2: wTm[n][768] = [B0 | B1 | R] rows; + biasM fills
__global__ __launch_bounds__(256) void prep_k(
    const float* __restrict__ b1, const float* __restrict__ r1, const float* __restrict__ bias1,
    const float* __restrict__ b2, const float* __restrict__ r2, const float* __restrict__ bias2,
    unsigned short* __restrict__ wTm1, unsigned short* __restrict__ wTm2,
    float* __restrict__ biasM1, float* __restrict__ biasM2)
{
    int b = blockIdx.x;
    int n = threadIdx.x;
    if (b < 1536) {
        int layer = b / 768;
        int rem = b % 768;
        int seg = rem / 256;
        int k = rem % 256;
        const float* bb = layer ? b2 : b1;
        const float* rr = layer ? r2 : r1;
        const float* in = (seg < 2) ? (bb + (size_t)seg * 256 * 256) : rr;
        unsigned short* out = layer ? wTm2 : wTm1;
        out[(size_t)n * 768 + seg * 256 + k] = f2bf(in[(size_t)k * 256 + n]);
    } else {
        int layer = b - 1536;
        float* bm = layer ? biasM2 : biasM1;
        const float* bs = layer ? bias2 : bias1;
        bm[n] = bs[n];
    }
}

// bf16 y -> BN(scale/shift from bns, computed in-block) + relu -> bf16 x into
// next layer's buf (stride 768, offset 512), or f32 d_out. 8 cols/thread.
template<bool LAST>
__global__ __launch_bounds__(256) void apply_k(const unsigned short* __restrict__ y,
                                               const float* __restrict__ bns,
                                               const float* __restrict__ gamma,
                                               const float* __restrict__ beta,
                                               unsigned short* __restrict__ xn,
                                               float* __restrict__ outp)
{
    __shared__ float scsh[512];
    {
        const float inv_m = 1.f / (float)M_REAL;
        int c = threadIdx.x;
        float m1 = bns[c] * inv_m;
        float var = fmaxf(bns[256 + c] * inv_m - m1 * m1, 0.f);
        float inv = rsqrtf(var + BN_EPS);
        float sc = gamma[c] * inv;
        scsh[c] = sc;
        scsh[256 + c] = beta[c] - m1 * sc;
    }
    __syncthreads();

    int i = blockIdx.x * 256 + threadIdx.x;
    int row = i >> 5;
    int c8 = (i & 31) * 8;
    short8 v = *(const short8*)(y + (size_t)row * 256 + c8);
    f4 sca = *(const f4*)&scsh[c8];
    f4 scb = *(const f4*)&scsh[c8 + 4];
    f4 sha = *(const f4*)&scsh[256 + c8];
    f4 shb = *(const f4*)&scsh[256 + c8 + 4];
    float o0 = fmaxf(bf2f((unsigned short)v[0]) * sca.x + sha.x, 0.f);
    float o1 = fmaxf(bf2f((unsigned short)v[1]) * sca.y + sha.y, 0.f);
    float o2 = fmaxf(bf2f((unsigned short)v[2]) * sca.z + sha.z, 0.f);
    float o3 = fmaxf(bf2f((unsigned short)v[3]) * sca.w + sha.w, 0.f);
    float o4 = fmaxf(bf2f((unsigned short)v[4]) * scb.x + shb.x, 0.f);
    float o5 = fmaxf(bf2f((unsigned short)v[5]) * scb.y + shb.y, 0.f);
    float o6 = fmaxf(bf2f((unsigned short)v[6]) * scb.z + shb.z, 0.f);
    float o7 = fmaxf(bf2f((unsigned short)v[7]) * scb.w + shb.w, 0.f);
    if (LAST) {
        f4 w0 = {o0, o1, o2, o3};
        f4 w1 = {o4, o5, o6, o7};
        float* dst = outp + (size_t)row * 256 + c8;
        *(f4*)dst = w0;
        *(f4*)(dst + 4) = w1;
    } else {
        short8 u;
        u[0] = (short)f2bf(o0); u[1] = (short)f2bf(o1);
        u[2] = (short)f2bf(o2); u[3] = (short)f2bf(o3);
        u[4] = (short)f2bf(o4); u[5] = (short)f2bf(o5);
        u[6] = (short)f2bf(o6); u[7] = (short)f2bf(o7);
        *(short8*)(xn + (size_t)row * 768 + 512 + c8) = u;
    }
}

extern "C" void kernel_launch(void* const* d_in, const int* in_sizes, int n_in,
                              void* d_out, int out_size, void* d_ws, size_t ws_size,
                              hipStream_t stream)
{
    const int*   edge_index = (const int*)d_in[0];
    const int*   edge_type  = (const int*)d_in[1];
    const float* emb    = (const float*)d_in[2];
    const float* proj_w = (const float*)d_in[3];
    const float* proj_b = (const float*)d_in[4];
    const float* comp[3]  = {(const float*)d_in[5],  (const float*)d_in[11], (const float*)d_in[17]};
    const float* bases[3] = {(const float*)d_in[6],  (const float*)d_in[12], (const float*)d_in[18]};
    const float* root[3]  = {(const float*)d_in[7],  (const float*)d_in[13], (const float*)d_in[19]};
    const float* biasp[3] = {(const float*)d_in[8],  (const float*)d_in[14], (const float*)d_in[20]};
    const float* gamma[3] = {(const float*)d_in[9],  (const float*)d_in[15], (const float*)d_in[21]};
    const float* beta[3]  = {(const float*)d_in[10], (const float*)d_in[16], (const float*)d_in[22]};

    char* ws = (char*)d_ws;
    size_t off = 0;
    auto alloc = [&](size_t bytes) -> char* {
        char* p = ws + off;
        off = (off + bytes + 255) & ~(size_t)255;
        return p;
    };

    unsigned short* axl0 = (unsigned short*)alloc((size_t)NNODES * 448 * 2);
    unsigned short* axl1 = (unsigned short*)alloc((size_t)NNODES * 768 * 2);
    unsigned short* axl2 = (unsigned short*)alloc((size_t)NNODES * 768 * 2);
    unsigned short* y    = (unsigned short*)alloc((size_t)NNODES * 256 * 2);
    unsigned int*   cnt  = (unsigned int*)alloc((size_t)NNODES * NREL * 4);
    unsigned int*   cntd = (unsigned int*)alloc((size_t)NNODES * 4);
    unsigned int*   rowptr = (unsigned int*)alloc((size_t)(NNODES + 1) * 4);
    unsigned int*   cursor = (unsigned int*)alloc((size_t)NNODES * 4);
    unsigned int*   partial = (unsigned int*)alloc((size_t)NNODES * 4);
    unsigned int*   bsum = (unsigned int*)alloc(128 * 4);
    float2*         erec = (float2*)alloc((size_t)NEDGE * 8);
    float*          PT   = (float*)alloc((size_t)768 * 128 * 4);
    unsigned short* wTm0 = (unsigned short*)alloc((size_t)256 * 448 * 2);
    unsigned short* wTm1 = (unsigned short*)alloc((size_t)256 * 768 * 2);
    unsigned short* wTm2 = (unsigned short*)alloc((size_t)256 * 768 * 2);
    float* biasM = (float*)alloc(3 * 256 * 4);
    float* bns   = (float*)alloc(3 * 512 * 4);

    zero_k<<<3125, 256, 0, stream>>>(cnt, cntd, cursor, bns);
    norm_k<<<NNODES / 4, 256, 0, stream>>>(emb, axl0);
    cnt_k<<<(NEDGE + 255) / 256, 256, 0, stream>>>(edge_index, edge_type, cnt, cntd);
    scan1_k<<<SCAN_NB, SCAN_B, 0, stream>>>(cntd, partial, bsum);
    scan2_k<<<1, 128, 0, stream>>>(bsum);
    scan3_k<<<SCAN_NB, SCAN_B, 0, stream>>>(partial, bsum, rowptr);
    fill_k<<<(NEDGE + 255) / 256, 256, 0, stream>>>(edge_index, edge_type, cnt, rowptr,
                                                    cursor, erec);

    pt_k<<<768, 128, 0, stream>>>(proj_w, PT);
    pm_k<<<768, 128, 0, stream>>>(PT, proj_b, bases[0], root[0], biasp[0], wTm0, biasM);
    prep_k<<<1538, 256, 0, stream>>>(bases[1], root[1], biasp[1],
                                     bases[2], root[2], biasp[2],
                                     wTm1, wTm2, biasM + 256, biasM + 512);

    // ---- layer 0 (D=128, K=448 with t-chunk) ----
    gatheru_k<128, true><<<NNODES / 4, 256, 0, stream>>>(axl0, comp[0], rowptr, erec);
    gemm3_k<448><<<8 * RPX * 2, 256, 0, stream>>>(axl0, wTm0, biasM, y, bns);
    apply_k<false><<<(NNODES * 32) / 256, 256, 0, stream>>>(y, bns, gamma[0], beta[0],
                                                            axl1, nullptr);

    // ---- layer 1 (D=256, K=768) ----
    gatheru_k<256, false><<<NNODES / 4, 256, 0, stream>>>(axl1, comp[1], rowptr, erec);
    gemm3_k<768><<<8 * RPX * 2, 256, 0, stream>>>(axl1, wTm1, biasM + 256, y, bns + 512);
    apply_k<false><<<(NNODES * 32) / 256, 256, 0, stream>>>(y, bns + 512, gamma[1], beta[1],
                                                            axl2, nullptr);

    // ---- layer 2 (D=256, K=768) ----
    gatheru_k<256, false><<<NNODES / 4, 256, 0, stream>>>(axl2, comp[2], rowptr, erec);
    gemm3_k<768><<<8 * RPX * 2, 256, 0, stream>>>(axl2, wTm2, biasM + 512, y, bns + 1024);
    apply_k<true><<<(NNODES * 32) / 256, 256, 0, stream>>>(y, bns + 1024, gamma[2], beta[2],
                                                           nullptr, (float*)d_out);
}

// Round 7
// 483.468 us; speedup vs baseline: 2.0528x; 1.0699x over previous
//
#include <hip/hip_runtime.h>
#include <hip/hip_bf16.h>

#define NNODES 50000
#define NREL   16
#define NEDGE  400000
#define BN_EPS 1e-5f
#define M_REAL NNODES
#define MT256  196             /* ceil(50000/256) row-tiles */
#define SCAN_B 512
#define SCAN_NB ((NNODES + SCAN_B - 1) / SCAN_B)   /* 98 */

typedef __attribute__((ext_vector_type(8))) short short8;
typedef __attribute__((ext_vector_type(4))) float f4;

__device__ __forceinline__ float bf2f(unsigned short u) {
    union { unsigned int i; float f; } x; x.i = ((unsigned int)u) << 16; return x.f;
}
__device__ __forceinline__ unsigned short f2bf(float f) {
    __hip_bfloat16 h = __float2bfloat16(f);
    union { __hip_bfloat16 h; unsigned short u; } x; x.h = h; return x.u;
}

__device__ __forceinline__ void g2l16(const unsigned short* g, unsigned short* l) {
    __builtin_amdgcn_global_load_lds(
        (const __attribute__((address_space(1))) unsigned int*)g,
        (__attribute__((address_space(3))) unsigned int*)l,
        16, 0, 0);
}

// ---------------------------------------------------------------------------
// GEMM: y[M,256](bf16) = A[M,K] @ WT[256,K]^T + bias, + BN sums (atomics).
// R7: tile 256x256 (BM=256, BN=full 256), 512 threads / 8 waves (2M x 4N,
// per-wave 128x64), BK=64, double-buffered. Rationale: R6 falsified the
// latency theory (dbuf +2.7% only); model says staging-BW-bound on L2/L3
// (~300MB logical @ 5.8 TB/s). 256x256 halves staged traffic (~154MB):
// A staged once (was 2x), B per-block doubles but block count halves.
// LDS 128KB -> 1 block/CU; grid 196 <= 256 CUs so no co-residency loss.
// No XCD swizzle: A has no inter-block reuse; B (393KB) L2-fits everywhere.
// ---------------------------------------------------------------------------
template<int K>
__global__ __launch_bounds__(512) void gemm3_k(
    const unsigned short* __restrict__ A,
    const unsigned short* __restrict__ WT,
    const float* __restrict__ bias,
    unsigned short* __restrict__ y,
    float* __restrict__ bns)
{
    const int tile_m = blockIdx.x * 256;

    __shared__ unsigned short As[2][256 * 64];
    __shared__ unsigned short Bs[2][256 * 64];

    const int w = threadIdx.x >> 6;       // 0..7
    const int l = threadIdx.x & 63;
    const int lm = l & 15;
    const int kq = l >> 4;
    const int wm = (w & 1) << 7;          // 0,128   (row group)
    const int wn = (w >> 1) << 6;         // 0,64,128,192 (col group)

    const int lrow = l >> 3;
    const int chunk = ((l & 7) + 8 - lrow) & 7;
    const unsigned short* srcA[4];
    const unsigned short* srcB[4];
    int dstoff[4];
#pragma unroll
    for (int it = 0; it < 4; ++it) {
        int rt = it * 64 + w * 8 + lrow;          // 0..255
        int rg = tile_m + rt; if (rg >= M_REAL) rg = M_REAL - 1;
        srcA[it] = A  + (size_t)rg * K + chunk * 8;
        srcB[it] = WT + (size_t)rt * K + chunk * 8;
        dstoff[it] = (it * 64 + w * 8) * 64;
    }

    unsigned aoff[8], boff[4];
#pragma unroll
    for (int mi = 0; mi < 8; ++mi)
        aoff[mi] = (unsigned)((wm + mi * 16 + lm) * 128 + (((kq + lm) & 7) << 4));
#pragma unroll
    for (int ni = 0; ni < 4; ++ni)
        boff[ni] = (unsigned)((wn + ni * 16 + lm) * 128 + (((kq + lm) & 7) << 4));

    f4 acc[8][4];
#pragma unroll
    for (int mi = 0; mi < 8; ++mi)
#pragma unroll
        for (int ni = 0; ni < 4; ++ni) acc[mi][ni] = (f4){0.f, 0.f, 0.f, 0.f};

    // prologue: stage tile 0 into buffer 0
#pragma unroll
    for (int it = 0; it < 4; ++it) {
        g2l16(srcA[it], As[0] + dstoff[it]);
        g2l16(srcB[it], Bs[0] + dstoff[it]);
    }
    __syncthreads();

    int cur = 0;
    for (int kc = 0; kc < K; kc += 64) {
        if (kc + 64 < K) {
#pragma unroll
            for (int it = 0; it < 4; ++it) {
                g2l16(srcA[it] + kc + 64, As[cur ^ 1] + dstoff[it]);
                g2l16(srcB[it] + kc + 64, Bs[cur ^ 1] + dstoff[it]);
            }
        }
#pragma unroll
        for (int kh = 0; kh < 2; ++kh) {
            const unsigned x = kh << 6;
            short8 af[8], bfr[4];
#pragma unroll
            for (int mi = 0; mi < 8; ++mi)
                af[mi] = *(const short8*)((const char*)As[cur] + (aoff[mi] ^ x));
#pragma unroll
            for (int ni = 0; ni < 4; ++ni)
                bfr[ni] = *(const short8*)((const char*)Bs[cur] + (boff[ni] ^ x));
#pragma unroll
            for (int mi = 0; mi < 8; ++mi)
#pragma unroll
                for (int ni = 0; ni < 4; ++ni)
                    acc[mi][ni] = __builtin_amdgcn_mfma_f32_16x16x32_bf16(
                        af[mi], bfr[ni], acc[mi][ni], 0, 0, 0);
        }
        __syncthreads();
        cur ^= 1;
    }

    int cols[4]; float bv[4];
#pragma unroll
    for (int ni = 0; ni < 4; ++ni) {
        cols[ni] = wn + ni * 16 + lm;
        bv[ni] = bias[cols[ni]];
    }
    float s1[4] = {0.f, 0.f, 0.f, 0.f}, s2[4] = {0.f, 0.f, 0.f, 0.f};
#pragma unroll
    for (int mi = 0; mi < 8; ++mi) {
#pragma unroll
        for (int rg = 0; rg < 4; ++rg) {
            int row = tile_m + wm + mi * 16 + kq * 4 + rg;
            if (row < M_REAL) {
                size_t base = (size_t)row * 256;
#pragma unroll
                for (int ni = 0; ni < 4; ++ni) {
                    float v = acc[mi][ni][rg] + bv[ni];
                    y[base + cols[ni]] = f2bf(v);
                    s1[ni] += v; s2[ni] += v * v;
                }
            }
        }
    }
#pragma unroll
    for (int ni = 0; ni < 4; ++ni) {
        float a = s1[ni], b = s2[ni];
        a += __shfl_xor(a, 16); a += __shfl_xor(a, 32);
        b += __shfl_xor(b, 16); b += __shfl_xor(b, 32);
        if (l < 16) {
            atomicAdd(&bns[cols[ni]], a);
            atomicAdd(&bns[256 + cols[ni]], b);
        }
    }
}

// ---------------------------------------------------------------------------
// gather in INPUT space: one wave per dst node; 4-edge unroll.
// buf row (stride S=3D(+64)): [u0 0..D | u1 D..2D | x 2D..3D | t-chunk (l0)]
// ---------------------------------------------------------------------------
template<int D, bool HAST>
__global__ __launch_bounds__(256) void gatheru_k(
    unsigned short* buf, const float* __restrict__ comp,
    const unsigned int* __restrict__ rowptr, const float2* __restrict__ erec)
{
    constexpr int E = D / 64;                 // bf16 elems per lane (2 or 4)
    constexpr int S = 3 * D + (HAST ? 64 : 0);
    __shared__ float scomp[32];
    if (threadIdx.x < 32) scomp[threadIdx.x] = comp[threadIdx.x];
    __syncthreads();
    int node = blockIdx.x * 4 + (threadIdx.x >> 6);
    int lane = threadIdx.x & 63;
    unsigned int p0 = rowptr[node], p1 = rowptr[node + 1];
    const unsigned short* xbase = buf + 2 * D + lane * E;

    float a0[E], a1[E], b0[E], b1[E];
#pragma unroll
    for (int e = 0; e < E; ++e) { a0[e] = a1[e] = b0[e] = b1[e] = 0.f; }
    float t0 = 0.f, t1 = 0.f;

    unsigned int p = p0;
    for (; p + 4 <= p1; p += 4) {
        float2 r[4];
        unsigned short v[4][E];
#pragma unroll
        for (int j = 0; j < 4; ++j) r[j] = erec[p + j];
#pragma unroll
        for (int j = 0; j < 4; ++j) {
            unsigned q = __float_as_uint(r[j].x);
            const unsigned short* s = xbase + (size_t)(q >> 4) * S;
            if (E == 2) { ushort2 t = *(const ushort2*)s; v[j][0] = t.x; v[j][1] = t.y; }
            else        { ushort4 t = *(const ushort4*)s; v[j][0] = t.x; v[j][1] = t.y;
                          v[j][2] = t.z; v[j][3] = t.w; }
        }
#pragma unroll
        for (int j = 0; j < 4; ++j) {
            unsigned q = __float_as_uint(r[j].x);
            float w0 = scomp[(q & 15) * 2] * r[j].y;
            float w1 = scomp[(q & 15) * 2 + 1] * r[j].y;
            if (HAST) { t0 += w0; t1 += w1; }
            float* d0 = (j & 1) ? b0 : a0;
            float* d1 = (j & 1) ? b1 : a1;
#pragma unroll
            for (int e = 0; e < E; ++e) {
                float xv = bf2f(v[j][e]);
                d0[e] += w0 * xv;
                d1[e] += w1 * xv;
            }
        }
    }
    for (; p < p1; ++p) {
        float2 r = erec[p];
        unsigned q = __float_as_uint(r.x);
        const unsigned short* s = xbase + (size_t)(q >> 4) * S;
        unsigned short v[E];
        if (E == 2) { ushort2 t = *(const ushort2*)s; v[0] = t.x; v[1] = t.y; }
        else        { ushort4 t = *(const ushort4*)s; v[0] = t.x; v[1] = t.y;
                      v[2] = t.z; v[3] = t.w; }
        float w0 = scomp[(q & 15) * 2] * r.y;
        float w1 = scomp[(q & 15) * 2 + 1] * r.y;
        if (HAST) { t0 += w0; t1 += w1; }
#pragma unroll
        for (int e = 0; e < E; ++e) {
            float xv = bf2f(v[e]);
            a0[e] += w0 * xv;
            a1[e] += w1 * xv;
        }
    }

    unsigned short* orow = buf + (size_t)node * S;
    if (E == 2) {
        ushort2 o0, o1;
        o0.x = f2bf(a0[0] + b0[0]); o0.y = f2bf(a0[1] + b0[1]);
        o1.x = f2bf(a1[0] + b1[0]); o1.y = f2bf(a1[1] + b1[1]);
        *(ushort2*)(orow + lane * 2) = o0;
        *(ushort2*)(orow + D + lane * 2) = o1;
    } else {
        ushort4 o0, o1;
        o0.x = f2bf(a0[0] + b0[0]); o0.y = f2bf(a0[1] + b0[1]);
        o0.z = f2bf(a0[2] + b0[2]); o0.w = f2bf(a0[3] + b0[3]);
        o1.x = f2bf(a1[0] + b1[0]); o1.y = f2bf(a1[1] + b1[1]);
        o1.z = f2bf(a1[2] + b1[2]); o1.w = f2bf(a1[3] + b1[3]);
        *(ushort4*)(orow + lane * 4) = o0;
        *(ushort4*)(orow + D + lane * 4) = o1;
    }
    if (HAST) {
        unsigned short tv = (lane == 0) ? f2bf(t0) : (lane == 1) ? f2bf(t1) : (unsigned short)0;
        orow[3 * D + lane] = tv;
    }
}

// row L2-normalize emb -> bf16 x0, into axl0 at col offset 256 (stride 448)
__global__ __launch_bounds__(256) void norm_k(const float* __restrict__ emb,
                                              unsigned short* __restrict__ buf)
{
    int node = blockIdx.x * 4 + (threadIdx.x >> 6);
    int lane = threadIdx.x & 63;
    const float2* p = (const float2*)(emb + (size_t)node * 128);
    float2 v = p[lane];
    float ss = v.x * v.x + v.y * v.y;
#pragma unroll
    for (int o = 32; o > 0; o >>= 1) ss += __shfl_xor(ss, o);
    float inv = 1.f / fmaxf(sqrtf(ss), 1e-12f);
    unsigned short* row = buf + (size_t)node * 448 + 256;
    unsigned int pack = (unsigned int)f2bf(v.x * inv) | ((unsigned int)f2bf(v.y * inv) << 16);
    ((unsigned int*)row)[lane] = pack;
}

// zero cnt(800000) cntd(50000) cursor(50000) bns(1536)
__global__ void zero_k(unsigned int* __restrict__ cnt, unsigned int* __restrict__ cntd,
                       unsigned int* __restrict__ cursor, float* __restrict__ bns)
{
    int i = blockIdx.x * 256 + threadIdx.x;
    if (i < 800000) cnt[i] = 0u;
    if (i < 50000) { cntd[i] = 0u; cursor[i] = 0u; }
    if (i < 1536) bns[i] = 0.f;
}

__global__ void cnt_k(const int* __restrict__ ei, const int* __restrict__ et,
                      unsigned int* __restrict__ cnt, unsigned int* __restrict__ cntd)
{
    int e = blockIdx.x * 256 + threadIdx.x;
    if (e >= NEDGE) return;
    int dst = ei[NEDGE + e];
    atomicAdd(&cnt[(size_t)dst * NREL + et[e]], 1u);
    atomicAdd(&cntd[dst], 1u);
}

__global__ __launch_bounds__(SCAN_B) void scan1_k(const unsigned int* __restrict__ cntd,
                                                  unsigned int* __restrict__ partial,
                                                  unsigned int* __restrict__ bsum)
{
    __shared__ unsigned int s[SCAN_B];
    int i = blockIdx.x * SCAN_B + threadIdx.x;
    unsigned int v = (i < NNODES) ? cntd[i] : 0u;
    s[threadIdx.x] = v;
    __syncthreads();
    for (int off = 1; off < SCAN_B; off <<= 1) {
        unsigned int t = (threadIdx.x >= off) ? s[threadIdx.x - off] : 0u;
        __syncthreads();
        s[threadIdx.x] += t;
        __syncthreads();
    }
    if (i < NNODES) partial[i] = s[threadIdx.x];
    if (threadIdx.x == SCAN_B - 1) bsum[blockIdx.x] = s[SCAN_B - 1];
}

__global__ __launch_bounds__(128) void scan2_k(unsigned int* __restrict__ bsum)
{
    __shared__ unsigned int s[128];
    unsigned int v = (threadIdx.x < SCAN_NB) ? bsum[threadIdx.x] : 0u;
    s[threadIdx.x] = v;
    __syncthreads();
    for (int off = 1; off < 128; off <<= 1) {
        unsigned int t = (threadIdx.x >= off) ? s[threadIdx.x - off] : 0u;
        __syncthreads();
        s[threadIdx.x] += t;
        __syncthreads();
    }
    if (threadIdx.x < SCAN_NB) bsum[threadIdx.x] = s[threadIdx.x];
}

__global__ __launch_bounds__(SCAN_B) void scan3_k(const unsigned int* __restrict__ partial,
                                                  const unsigned int* __restrict__ bsum,
                                                  unsigned int* __restrict__ rowptr)
{
    int i = blockIdx.x * SCAN_B + threadIdx.x;
    if (i >= NNODES) return;
    unsigned int off = (blockIdx.x > 0) ? bsum[blockIdx.x - 1] : 0u;
    rowptr[i + 1] = partial[i] + off;
    if (i == 0) rowptr[0] = 0u;
}

__global__ void fill_k(const int* __restrict__ ei, const int* __restrict__ et,
                       const unsigned int* __restrict__ cnt,
                       const unsigned int* __restrict__ rowptr,
                       unsigned int* __restrict__ cursor,
                       float2* __restrict__ erec)
{
    int e = blockIdx.x * 256 + threadIdx.x;
    if (e >= NEDGE) return;
    int dst = ei[NEDGE + e];
    int t = et[e];
    unsigned int c = cnt[(size_t)dst * NREL + t];
    unsigned int pos = rowptr[dst] + atomicAdd(&cursor[dst], 1u);
    float2 r;
    r.x = __uint_as_float(((unsigned)ei[e] << 4) | (unsigned)t);
    r.y = 1.f / (float)(c ? c : 1u);
    erec[pos] = r;
}

// PT[j*128+d] = proj_w[d*768+j]
__global__ __launch_bounds__(128) void pt_k(const float* __restrict__ proj_w,
                                            float* __restrict__ PT)
{
    int j = blockIdx.x, d = threadIdx.x;
    PT[(size_t)j * 128 + d] = proj_w[(size_t)d * 768 + j];
}

// layer-0 folded weights: wTm0[n][448]: [P@B0 | P@B1 | P@R | pb@B0, pb@B1, 0..]
__global__ __launch_bounds__(128) void pm_k(
    const float* __restrict__ PT, const float* __restrict__ pb,
    const float* __restrict__ b0, const float* __restrict__ r0,
    const float* __restrict__ bias0,
    unsigned short* __restrict__ wTm0, float* __restrict__ biasM0)
{
    __shared__ float sw[128];
    __shared__ float spb[128];
    __shared__ float red[2];
    int seg = blockIdx.x >> 8;
    int n = blockIdx.x & 255;
    int d = threadIdx.x;
    float acc = 0.f, accb = 0.f;
    for (int ch = 0; ch < 6; ++ch) {
        int j0 = ch * 128;
        __syncthreads();
        int j = j0 + d;
        float wv;
        if (seg == 0)      wv = b0[(size_t)j * 256 + n];
        else if (seg == 1) wv = b0[768 * 256 + (size_t)j * 256 + n];
        else               wv = r0[(size_t)j * 256 + n];
        sw[d] = wv;
        spb[d] = pb[j];
        __syncthreads();
#pragma unroll 8
        for (int jj = 0; jj < 128; ++jj)
            acc += PT[(size_t)(j0 + jj) * 128 + d] * sw[jj];
        accb += spb[d] * sw[d];
    }
    for (int o = 32; o > 0; o >>= 1) accb += __shfl_xor(accb, o);
    if ((d & 63) == 0) red[d >> 6] = accb;
    __syncthreads();
    float tb = red[0] + red[1];
    wTm0[(size_t)n * 448 + seg * 128 + d] = f2bf(acc);
    if (seg == 0) { if (d == 0) wTm0[(size_t)n * 448 + 384] = f2bf(tb); }
    else if (seg == 1) { if (d == 0) wTm0[(size_t)n * 448 + 385] = f2bf(tb); }
    else {
        if (d == 0) biasM0[n] = tb + bias0[n];
        if (d >= 2 && d < 64) wTm0[(size_t)n * 448 + 384 + d] = 0;
    }
}

// layers 1/2: wTm[n][768] = [B0 | B1 | R] rows; + biasM fills
__global__ __launch_bounds__(256) void prep_k(
    const float* __restrict__ b1, const float* __restrict__ r1, const float* __restrict__ bias1,
    const float* __restrict__ b2, const float* __restrict__ r2, const float* __restrict__ bias2,
    unsigned short* __restrict__ wTm1, unsigned short* __restrict__ wTm2,
    float* __restrict__ biasM1, float* __restrict__ biasM2)
{
    int b = blockIdx.x;
    int n = threadIdx.x;
    if (b < 1536) {
        int layer = b / 768;
        int rem = b % 768;
        int seg = rem / 256;
        int k = rem % 256;
        const float* bb = layer ? b2 : b1;
        const float* rr = layer ? r2 : r1;
        const float* in = (seg < 2) ? (bb + (size_t)seg * 256 * 256) : rr;
        unsigned short* out = layer ? wTm2 : wTm1;
        out[(size_t)n * 768 + seg * 256 + k] = f2bf(in[(size_t)k * 256 + n]);
    } else {
        int layer = b - 1536;
        float* bm = layer ? biasM2 : biasM1;
        const float* bs = layer ? bias2 : bias1;
        bm[n] = bs[n];
    }
}

// bf16 y -> BN(scale/shift from bns, computed in-block) + relu -> bf16 x into
// next layer's buf (stride 768, offset 512), or f32 d_out. 8 cols/thread.
template<bool LAST>
__global__ __launch_bounds__(256) void apply_k(const unsigned short* __restrict__ y,
                                               const float* __restrict__ bns,
                                               const float* __restrict__ gamma,
                                               const float* __restrict__ beta,
                                               unsigned short* __restrict__ xn,
                                               float* __restrict__ outp)
{
    __shared__ float scsh[512];
    {
        const float inv_m = 1.f / (float)M_REAL;
        int c = threadIdx.x;
        float m1 = bns[c] * inv_m;
        float var = fmaxf(bns[256 + c] * inv_m - m1 * m1, 0.f);
        float inv = rsqrtf(var + BN_EPS);
        float sc = gamma[c] * inv;
        scsh[c] = sc;
        scsh[256 + c] = beta[c] - m1 * sc;
    }
    __syncthreads();

    int i = blockIdx.x * 256 + threadIdx.x;
    int row = i >> 5;
    int c8 = (i & 31) * 8;
    short8 v = *(const short8*)(y + (size_t)row * 256 + c8);
    f4 sca = *(const f4*)&scsh[c8];
    f4 scb = *(const f4*)&scsh[c8 + 4];
    f4 sha = *(const f4*)&scsh[256 + c8];
    f4 shb = *(const f4*)&scsh[256 + c8 + 4];
    float o0 = fmaxf(bf2f((unsigned short)v[0]) * sca.x + sha.x, 0.f);
    float o1 = fmaxf(bf2f((unsigned short)v[1]) * sca.y + sha.y, 0.f);
    float o2 = fmaxf(bf2f((unsigned short)v[2]) * sca.z + sha.z, 0.f);
    float o3 = fmaxf(bf2f((unsigned short)v[3]) * sca.w + sha.w, 0.f);
    float o4 = fmaxf(bf2f((unsigned short)v[4]) * scb.x + shb.x, 0.f);
    float o5 = fmaxf(bf2f((unsigned short)v[5]) * scb.y + shb.y, 0.f);
    float o6 = fmaxf(bf2f((unsigned short)v[6]) * scb.z + shb.z, 0.f);
    float o7 = fmaxf(bf2f((unsigned short)v[7]) * scb.w + shb.w, 0.f);
    if (LAST) {
        f4 w0 = {o0, o1, o2, o3};
        f4 w1 = {o4, o5, o6, o7};
        float* dst = outp + (size_t)row * 256 + c8;
        *(f4*)dst = w0;
        *(f4*)(dst + 4) = w1;
    } else {
        short8 u;
        u[0] = (short)f2bf(o0); u[1] = (short)f2bf(o1);
        u[2] = (short)f2bf(o2); u[3] = (short)f2bf(o3);
        u[4] = (short)f2bf(o4); u[5] = (short)f2bf(o5);
        u[6] = (short)f2bf(o6); u[7] = (short)f2bf(o7);
        *(short8*)(xn + (size_t)row * 768 + 512 + c8) = u;
    }
}

extern "C" void kernel_launch(void* const* d_in, const int* in_sizes, int n_in,
                              void* d_out, int out_size, void* d_ws, size_t ws_size,
                              hipStream_t stream)
{
    const int*   edge_index = (const int*)d_in[0];
    const int*   edge_type  = (const int*)d_in[1];
    const float* emb    = (const float*)d_in[2];
    const float* proj_w = (const float*)d_in[3];
    const float* proj_b = (const float*)d_in[4];
    const float* comp[3]  = {(const float*)d_in[5],  (const float*)d_in[11], (const float*)d_in[17]};
    const float* bases[3] = {(const float*)d_in[6],  (const float*)d_in[12], (const float*)d_in[18]};
    const float* root[3]  = {(const float*)d_in[7],  (const float*)d_in[13], (const float*)d_in[19]};
    const float* biasp[3] = {(const float*)d_in[8],  (const float*)d_in[14], (const float*)d_in[20]};
    const float* gamma[3] = {(const float*)d_in[9],  (const float*)d_in[15], (const float*)d_in[21]};
    const float* beta[3]  = {(const float*)d_in[10], (const float*)d_in[16], (const float*)d_in[22]};

    char* ws = (char*)d_ws;
    size_t off = 0;
    auto alloc = [&](size_t bytes) -> char* {
        char* p = ws + off;
        off = (off + bytes + 255) & ~(size_t)255;
        return p;
    };

    unsigned short* axl0 = (unsigned short*)alloc((size_t)NNODES * 448 * 2);
    unsigned short* axl1 = (unsigned short*)alloc((size_t)NNODES * 768 * 2);
    unsigned short* axl2 = (unsigned short*)alloc((size_t)NNODES * 768 * 2);
    unsigned short* y    = (unsigned short*)alloc((size_t)NNODES * 256 * 2);
    unsigned int*   cnt  = (unsigned int*)alloc((size_t)NNODES * NREL * 4);
    unsigned int*   cntd = (unsigned int*)alloc((size_t)NNODES * 4);
    unsigned int*   rowptr = (unsigned int*)alloc((size_t)(NNODES + 1) * 4);
    unsigned int*   cursor = (unsigned int*)alloc((size_t)NNODES * 4);
    unsigned int*   partial = (unsigned int*)alloc((size_t)NNODES * 4);
    unsigned int*   bsum = (unsigned int*)alloc(128 * 4);
    float2*         erec = (float2*)alloc((size_t)NEDGE * 8);
    float*          PT   = (float*)alloc((size_t)768 * 128 * 4);
    unsigned short* wTm0 = (unsigned short*)alloc((size_t)256 * 448 * 2);
    unsigned short* wTm1 = (unsigned short*)alloc((size_t)256 * 768 * 2);
    unsigned short* wTm2 = (unsigned short*)alloc((size_t)256 * 768 * 2);
    float* biasM = (float*)alloc(3 * 256 * 4);
    float* bns   = (float*)alloc(3 * 512 * 4);

    zero_k<<<3125, 256, 0, stream>>>(cnt, cntd, cursor, bns);
    norm_k<<<NNODES / 4, 256, 0, stream>>>(emb, axl0);
    cnt_k<<<(NEDGE + 255) / 256, 256, 0, stream>>>(edge_index, edge_type, cnt, cntd);
    scan1_k<<<SCAN_NB, SCAN_B, 0, stream>>>(cntd, partial, bsum);
    scan2_k<<<1, 128, 0, stream>>>(bsum);
    scan3_k<<<SCAN_NB, SCAN_B, 0, stream>>>(partial, bsum, rowptr);
    fill_k<<<(NEDGE + 255) / 256, 256, 0, stream>>>(edge_index, edge_type, cnt, rowptr,
                                                    cursor, erec);

    pt_k<<<768, 128, 0, stream>>>(proj_w, PT);
    pm_k<<<768, 128, 0, stream>>>(PT, proj_b, bases[0], root[0], biasp[0], wTm0, biasM);
    prep_k<<<1538, 256, 0, stream>>>(bases[1], root[1], biasp[1],
                                     bases[2], root[2], biasp[2],
                                     wTm1, wTm2, biasM + 256, biasM + 512);

    // ---- layer 0 (D=128, K=448 with t-chunk) ----
    gatheru_k<128, true><<<NNODES / 4, 256, 0, stream>>>(axl0, comp[0], rowptr, erec);
    gemm3_k<448><<<MT256, 512, 0, stream>>>(axl0, wTm0, biasM, y, bns);
    apply_k<false><<<(NNODES * 32) / 256, 256, 0, stream>>>(y, bns, gamma[0], beta[0],
                                                            axl1, nullptr);

    // ---- layer 1 (D=256, K=768) ----
    gatheru_k<256, false><<<NNODES / 4, 256, 0, stream>>>(axl1, comp[1], rowptr, erec);
    gemm3_k<768><<<MT256, 512, 0, stream>>>(axl1, wTm1, biasM + 256, y, bns + 512);
    apply_k<false><<<(NNODES * 32) / 256, 256, 0, stream>>>(y, bns + 512, gamma[1], beta[1],
                                                            axl2, nullptr);

    // ---- layer 2 (D=256, K=768) ----
    gatheru_k<256, false><<<NNODES / 4, 256, 0, stream>>>(axl2, comp[2], rowptr, erec);
    gemm3_k<768><<<MT256, 512, 0, stream>>>(axl2, wTm2, biasM + 512, y, bns + 1024);
    apply_k<true><<<(NNODES * 32) / 256, 256, 0, stream>>>(y, bns + 1024, gamma[2], beta[2],
                                                           nullptr, (float*)d_out);
}